// Round 11
// baseline (1926.114 us; speedup 1.0000x reference)
//
#include <hip/hip_runtime.h>
#include <cstdint>
#include <cstddef>
#include <cmath>

#define N_ROWS 30000
#define D_IN   784
#define NC     100
#define NCP    128
#define NSEG   12
#define SEG    30000
#define SORT_BLOCKS 118   // ceil(30000/256)
#define KP     800        // K padded to multiple of 32
#define MAXBLK 435        // ceil(27826/64)
#define SL     16         // row-slices for k_dotQ

typedef short bf16x8 __attribute__((ext_vector_type(8)));
typedef float f32x4  __attribute__((ext_vector_type(4)));

struct Hdr {
  uint32_t kperm[12][2];
  uint32_t kw[12][2];
  uint32_t kb[12][2];
  uint32_t sub[12][2][2];
  int best; int pad0;
  float bsel;
  float r2arr[12];       // column norms of unnormalized Q columns
  float r1s[12 * SL];    // Q^T hc raw partials, SL slices per j
  float r1bs[12 * SL];   // reorth raw partials
  float R[144];      // 12x12 row-major
  float QT[120];     // 12x10
  float beta[120];   // 12x10
  float den[100];
  float num[1000];   // [c][j]
};

__device__ __forceinline__ void tf2x32(uint32_t k0, uint32_t k1,
                                       uint32_t x0, uint32_t x1,
                                       uint32_t& o0, uint32_t& o1) {
  const uint32_t kx = k0 ^ k1 ^ 0x1BD11BDAu;
  x0 += k0; x1 += k1;
  x0 += x1; x1 = (x1<<13)|(x1>>19); x1 ^= x0;
  x0 += x1; x1 = (x1<<15)|(x1>>17); x1 ^= x0;
  x0 += x1; x1 = (x1<<26)|(x1>>6);  x1 ^= x0;
  x0 += x1; x1 = (x1<<6) |(x1>>26); x1 ^= x0;
  x0 += k1; x1 += kx + 1u;
  x0 += x1; x1 = (x1<<17)|(x1>>15); x1 ^= x0;
  x0 += x1; x1 = (x1<<29)|(x1>>3);  x1 ^= x0;
  x0 += x1; x1 = (x1<<16)|(x1>>16); x1 ^= x0;
  x0 += x1; x1 = (x1<<24)|(x1>>8);  x1 ^= x0;
  x0 += kx; x1 += k0 + 2u;
  x0 += x1; x1 = (x1<<13)|(x1>>19); x1 ^= x0;
  x0 += x1; x1 = (x1<<15)|(x1>>17); x1 ^= x0;
  x0 += x1; x1 = (x1<<26)|(x1>>6);  x1 ^= x0;
  x0 += x1; x1 = (x1<<6) |(x1>>26); x1 ^= x0;
  x0 += k0; x1 += k1 + 3u;
  x0 += x1; x1 = (x1<<17)|(x1>>15); x1 ^= x0;
  x0 += x1; x1 = (x1<<29)|(x1>>3);  x1 ^= x0;
  x0 += x1; x1 = (x1<<16)|(x1>>16); x1 ^= x0;
  x0 += x1; x1 = (x1<<24)|(x1>>8);  x1 ^= x0;
  x0 += k1; x1 += kx + 4u;
  x0 += x1; x1 = (x1<<13)|(x1>>19); x1 ^= x0;
  x0 += x1; x1 = (x1<<15)|(x1>>17); x1 ^= x0;
  x0 += x1; x1 = (x1<<26)|(x1>>6);  x1 ^= x0;
  x0 += x1; x1 = (x1<<6) |(x1>>26); x1 ^= x0;
  x0 += kx; x1 += k0 + 5u;
  o0 = x0; o1 = x1;
}

__device__ __forceinline__ float u01(uint32_t bits) {
  return __uint_as_float((bits >> 9) | 0x3f800000u) - 1.0f;
}

__device__ __forceinline__ uint32_t rbits32(uint32_t k0, uint32_t k1, uint32_t idx) {
  uint32_t o0, o1;
  tf2x32(k0, k1, 0u, idx, o0, o1);
  return o0 ^ o1;
}

__device__ __forceinline__ ushort f2bf_rne(float f) {
  uint32_t u = __float_as_uint(f);
  return (ushort)((u + 0x7fffu + ((u >> 16) & 1u)) >> 16);
}
__device__ __forceinline__ float bf2f(ushort h) {
  return __uint_as_float(((uint32_t)h) << 16);
}

// ---------------- RNG key chain (jax_threefry_partitionable=True) ----------------
__global__ void k_rng_chain(Hdr* h) {
  if (threadIdx.x != 0 || blockIdx.x != 0) return;
  uint32_t c0 = 0u, c1 = 42u;
  for (int k = 0; k < 12; k++) {
    uint32_t t0, t1;
    tf2x32(c0, c1, 0u, 1u, t0, t1); h->kperm[k][0] = t0; h->kperm[k][1] = t1;
    tf2x32(c0, c1, 0u, 2u, t0, t1); h->kw[k][0]   = t0; h->kw[k][1]   = t1;
    tf2x32(c0, c1, 0u, 3u, t0, t1); h->kb[k][0]   = t0; h->kb[k][1]   = t1;
    uint32_t p0 = h->kperm[k][0], p1 = h->kperm[k][1];
    for (int r = 0; r < 2; r++) {
      uint32_t s0, s1, n0, n1;
      tf2x32(p0, p1, 0u, 1u, s0, s1);
      tf2x32(p0, p1, 0u, 0u, n0, n1);
      h->sub[k][r][0] = s0; h->sub[k][r][1] = s1;
      p0 = n0; p1 = n1;
    }
    tf2x32(c0, c1, 0u, 0u, t0, t1); c0 = t0; c1 = t1;
  }
}

// ---------------- X pre-split to bf16 hi/lo, KP-padded ----------------
__global__ __launch_bounds__(256) void k_splitX(const float* __restrict__ X,
    short* __restrict__ Xhi, short* __restrict__ Xlo) {
  int t = blockIdx.x * 256 + threadIdx.x;       // one thread per 8-elem group
  if (t >= N_ROWS * (KP / 8)) return;
  int i = t / (KP / 8), g = t % (KP / 8);
  int kb = g * 8;
  float v[8];
  if (kb + 8 <= D_IN) {
    const float* xr = X + (size_t)i * D_IN + kb;
    float4 p0 = *(const float4*)xr;
    float4 p1 = *(const float4*)(xr + 4);
    v[0]=p0.x; v[1]=p0.y; v[2]=p0.z; v[3]=p0.w;
    v[4]=p1.x; v[5]=p1.y; v[6]=p1.z; v[7]=p1.w;
  } else {
    #pragma unroll
    for (int q = 0; q < 8; q++) v[q] = 0.f;
  }
  uint32_t ph[4], pl[4];
  #pragma unroll
  for (int q = 0; q < 4; q++) {
    ushort h0 = f2bf_rne(v[2*q]),   h1 = f2bf_rne(v[2*q+1]);
    ushort l0 = f2bf_rne(v[2*q]   - bf2f(h0));
    ushort l1 = f2bf_rne(v[2*q+1] - bf2f(h1));
    ph[q] = (uint32_t)h0 | ((uint32_t)h1 << 16);
    pl[q] = (uint32_t)l0 | ((uint32_t)l1 << 16);
  }
  size_t o = (size_t)i * KP + kb;
  *(uint4*)(Xhi + o) = make_uint4(ph[0], ph[1], ph[2], ph[3]);
  *(uint4*)(Xlo + o) = make_uint4(pl[0], pl[1], pl[2], pl[3]);
}

// ---------------- radix sort (separate hist/scan/scatter) ----------------
// pass 0 of each round: generate keys (+iota vals on round 0) + hist(shift=0)
__global__ __launch_bounds__(256) void k_keys_hist(const Hdr* __restrict__ h,
    uint32_t* __restrict__ keys, int* __restrict__ vals,
    uint32_t* __restrict__ hs, int round) {
  __shared__ uint32_t hloc[256];
  int s = blockIdx.x / SORT_BLOCKS, b = blockIdx.x % SORT_BLOCKS;
  int tid = threadIdx.x;
  hloc[tid] = 0;
  __syncthreads();
  int i = b * 256 + tid;
  if (i < SEG) {
    uint32_t key = rbits32(h->sub[s][round][0], h->sub[s][round][1], (uint32_t)i);
    keys[s * SEG + i] = key;
    if (round == 0) vals[s * SEG + i] = i;
    atomicAdd(&hloc[key & 255u], 1u);
  }
  __syncthreads();
  hs[(size_t)(s * SORT_BLOCKS + b) * 256 + tid] = hloc[tid];
}

__global__ __launch_bounds__(256) void k_hist(const uint32_t* __restrict__ keys,
    uint32_t* __restrict__ hs, int shift) {
  __shared__ uint32_t hloc[256];
  int s = blockIdx.x / SORT_BLOCKS, b = blockIdx.x % SORT_BLOCKS;
  hloc[threadIdx.x] = 0;
  __syncthreads();
  int i = b * 256 + threadIdx.x;
  if (i < SEG) {
    uint32_t d = (keys[s * SEG + i] >> shift) & 255u;
    atomicAdd(&hloc[d], 1u);
  }
  __syncthreads();
  hs[(size_t)(s * SORT_BLOCKS + b) * 256 + threadIdx.x] = hloc[threadIdx.x];
}

// chunked pipelined scan; per-(s,block) local offsets + per-(s,digit) base
__global__ __launch_bounds__(256) void k_scan(uint32_t* hs, uint32_t* baseA) {
  __shared__ uint32_t tot[256];
  __shared__ uint32_t base[256];
  int s = blockIdx.x, d = threadIdx.x;
  uint32_t run = 0;
  uint32_t buf[30];
  for (int c0 = 0; c0 < SORT_BLOCKS; c0 += 30) {
    int n = SORT_BLOCKS - c0; if (n > 30) n = 30;
    #pragma unroll
    for (int j = 0; j < 30; j++)
      if (j < n) buf[j] = hs[(size_t)(s * SORT_BLOCKS + c0 + j) * 256 + d];
    #pragma unroll
    for (int j = 0; j < 30; j++)
      if (j < n) {
        uint32_t c = buf[j];
        hs[(size_t)(s * SORT_BLOCKS + c0 + j) * 256 + d] = run;
        run += c;
      }
  }
  tot[d] = run;
  __syncthreads();
  if (d == 0) {
    uint32_t acc = 0;
    for (int q = 0; q < 256; q++) { base[q] = acc; acc += tot[q]; }
  }
  __syncthreads();
  baseA[s * 256 + d] = base[d];
}

__global__ __launch_bounds__(256) void k_scatter(const uint32_t* __restrict__ ik,
    const int* __restrict__ iv, uint32_t* __restrict__ ok, int* __restrict__ ov,
    const uint32_t* __restrict__ hs, const uint32_t* __restrict__ baseA, int shift) {
  __shared__ uint16_t wh[4][256];
  int s = blockIdx.x / SORT_BLOCKS, b = blockIdx.x % SORT_BLOCKS;
  int tid = threadIdx.x;
  for (int q = tid; q < 1024; q += 256) ((uint16_t*)wh)[q] = 0;
  __syncthreads();
  int i = b * 256 + tid;
  bool valid = (i < SEG);
  uint32_t key = 0, dg = 0; int val = 0;
  if (valid) {
    key = ik[s * SEG + i];
    val = iv[s * SEG + i];
    dg = (key >> shift) & 255u;
  }
  unsigned long long vm = __ballot(valid ? 1 : 0);
  unsigned long long m = ~0ULL;
  for (int bit = 0; bit < 8; bit++) {
    unsigned long long bm = __ballot((int)((dg >> bit) & 1u));
    m &= ((dg >> bit) & 1u) ? bm : ~bm;
  }
  m &= vm;
  int wv = tid >> 6, lane = tid & 63;
  int rw = __popcll(m & ((1ULL << lane) - 1ULL));
  if (valid && rw == 0) wh[wv][dg] = (uint16_t)__popcll(m);
  __syncthreads();
  if (valid) {
    int rank = rw;
    for (int q = 0; q < wv; q++) rank += wh[q][dg];
    uint32_t pos = hs[(size_t)(s * SORT_BLOCKS + b) * 256 + dg] + baseA[s * 256 + dg] + rank;
    ok[s * SEG + pos] = key;
    ov[s * SEG + pos] = val;
  }
}

// ---------------- candidate weight generation (W + b fused) ----------------
__global__ __launch_bounds__(256) void k_gen(const Hdr* __restrict__ h,
    float* __restrict__ Wr, short* __restrict__ Wthi, short* __restrict__ Wtlo,
    float* __restrict__ br) {
  int t = blockIdx.x * 256 + threadIdx.x;
  if (t >= NSEG * NCP * KP) return;
  if (t < NSEG * NC) {
    int k = t / NC, c = t % NC;
    float u = u01(rbits32(h->kb[k][0], h->kb[k][1], (uint32_t)c));
    float lam = (c < 50) ? 1.f : 10.f;
    br[t] = lam * (2.f * u - 1.f);
  }
  int seg = t / (NCP * KP);
  int r = t % (NCP * KP);
  int c = r / KP, d = r % KP;
  float val = 0.f;
  if (c < NC && d < D_IN) {
    int n = d * NC + c;  // row-major linear index of (784,100)
    float u = u01(rbits32(h->kw[seg][0], h->kw[seg][1], (uint32_t)n));
    float lam = (c < 50) ? 1.f : 10.f;
    val = lam * (2.f * u - 1.f);
  }
  ushort hi = f2bf_rne(val);
  ushort lo = f2bf_rne(val - bf2f(hi));
  Wthi[t] = (short)hi;
  Wtlo[t] = (short)lo;
  if (d < D_IN) Wr[(size_t)seg * D_IN * NCP + (size_t)d * NCP + c] = val;
}

// ---- MFMA split-bf16 candidate GEMM; A/B fragments loaded DIRECTLY global->reg ----
// (no LDS tiles, no staging barriers: fragments are lane-contiguous 16B chunks of
//  the pre-split Xhi/Xlo [row][k] and Wthi/Wtlo [col][k] arrays; W is L2-resident,
//  X-split is L3-resident. Compiler pipelines loads across k-steps via vmcnt.)
__global__ __launch_bounds__(256) void k_batch_mfma(const short* __restrict__ Xhi,
    const short* __restrict__ Xlo,
    const short* __restrict__ Wthi, const short* __restrict__ Wtlo,
    const float* __restrict__ br, const int* __restrict__ perm,
    const float* __restrict__ Y, const float* __restrict__ Hbuf,
    const Hdr* __restrict__ hd, float* __restrict__ P, int kk, int bs) {
  __shared__ int idxs[64];
  __shared__ float ekS[64][10];
  __shared__ float hS[64][12];
  __shared__ float betaS[120];
  int tid = threadIdx.x;
  int row0 = blockIdx.x * 64;
  if (tid < 64) {
    int rr = row0 + tid;
    idxs[tid] = perm[rr < bs ? rr : (bs - 1)];
  }
  if (kk > 0 && tid < kk * 10) betaS[tid] = hd->beta[tid];
  __syncthreads();
  if (kk > 0) {
    for (int q = tid; q < 64 * kk; q += 256) {
      int r = q / kk, m = q % kk;
      hS[r][m] = Hbuf[(size_t)idxs[r] * 12 + m];
    }
  }
  __syncthreads();
  for (int q = tid; q < 640; q += 256) {
    int r = q / 10, j = q % 10;
    float e = 0.f;
    if (row0 + r < bs) {
      e = Y[(size_t)idxs[r] * 10 + j];
      if (kk > 0) {
        float yv = 0.f;
        for (int m = 0; m < kk; m++) yv += hS[r][m] * betaS[m * 10 + j];
        e -= yv;
      }
    }
    ekS[r][j] = e;
  }
  int wave = tid >> 6, lane = tid & 63;
  int kg = lane >> 4, ln = lane & 15;
  __syncthreads();

  // per-lane fragment base offsets (in shorts)
  size_t aoff[4];
  #pragma unroll
  for (int m = 0; m < 4; m++)
    aoff[m] = (size_t)idxs[m * 16 + ln] * KP + kg * 8;
  size_t boff[2];
  #pragma unroll
  for (int j = 0; j < 2; j++)
    boff[j] = (size_t)((2 * wave + j) * 16 + ln) * KP + kg * 8;

  f32x4 acc[4][2];
  #pragma unroll
  for (int m = 0; m < 4; m++)
    #pragma unroll
    for (int j = 0; j < 2; j++)
      acc[m][j] = (f32x4){0.f, 0.f, 0.f, 0.f};

  for (int k0 = 0; k0 < KP; k0 += 32) {
    bf16x8 bh[2], bl[2];
    #pragma unroll
    for (int j = 0; j < 2; j++) {
      bh[j] = *(const bf16x8*)(Wthi + boff[j] + k0);
      bl[j] = *(const bf16x8*)(Wtlo + boff[j] + k0);
    }
    #pragma unroll
    for (int m = 0; m < 4; m++) {
      bf16x8 ah = *(const bf16x8*)(Xhi + aoff[m] + k0);
      bf16x8 al = *(const bf16x8*)(Xlo + aoff[m] + k0);
      #pragma unroll
      for (int j = 0; j < 2; j++) {
        acc[m][j] = __builtin_amdgcn_mfma_f32_16x16x32_bf16(ah, bh[j], acc[m][j], 0, 0, 0);
        acc[m][j] = __builtin_amdgcn_mfma_f32_16x16x32_bf16(ah, bl[j], acc[m][j], 0, 0, 0);
        acc[m][j] = __builtin_amdgcn_mfma_f32_16x16x32_bf16(al, bh[j], acc[m][j], 0, 0, 0);
      }
    }
  }
  // ---- fused epilogue: sigmoid + den/num partials, plain stores to P ----
  // C/D layout: col=lane&15, row=(lane>>4)*4+reg. Lanes kg=0..3 share a column.
  #pragma unroll
  for (int j = 0; j < 2; j++) {
    int col = (2 * wave + j) * 16 + ln;
    float bias = (col < NC) ? br[col] : 0.f;
    float den_t = 0.f;
    float num_t[10];
    #pragma unroll
    for (int q = 0; q < 10; q++) num_t[q] = 0.f;
    #pragma unroll
    for (int m = 0; m < 4; m++) {
      #pragma unroll
      for (int r = 0; r < 4; r++) {
        int rl = m * 16 + kg * 4 + r;
        if (row0 + rl < bs) {
          float hsig = 1.f / (1.f + expf(-(acc[m][j][r] + bias)));
          den_t += hsig * hsig;
          #pragma unroll
          for (int q = 0; q < 10; q++) num_t[q] += hsig * ekS[rl][q];
        }
      }
    }
    den_t += __shfl_xor(den_t, 16, 64);
    den_t += __shfl_xor(den_t, 32, 64);
    #pragma unroll
    for (int q = 0; q < 10; q++) {
      num_t[q] += __shfl_xor(num_t[q], 16, 64);
      num_t[q] += __shfl_xor(num_t[q], 32, 64);
    }
    if (kg == 0 && col < NC) {
      float* dst = P + (size_t)blockIdx.x * 1100 + col * 11;
      dst[0] = den_t;
      #pragma unroll
      for (int q = 0; q < 10; q++) dst[1 + q] = num_t[q];
    }
  }
}

// ---- score reduce + select + wcol (merged via last-block ticket, 100 blocks) ----
__global__ __launch_bounds__(256) void k_score_select(const float* __restrict__ P,
    Hdr* h, const float* __restrict__ brk, const float* __restrict__ Wr,
    float* __restrict__ wcol, float* __restrict__ outW, float* __restrict__ outB,
    int* __restrict__ ticket, int k, int nblk) {
  int c = blockIdx.x;           // 0..99
  int tid = threadIdx.x;
  int q = tid % 11, g = tid / 11;   // 23 groups of 11
  float acc = 0.f;
  if (tid < 253) {
    for (int b = g; b < nblk; b += 23)
      acc += P[(size_t)b * 1100 + c * 11 + q];
  }
  __shared__ float red[23][11];
  if (tid < 253) red[g][q] = acc;
  __syncthreads();
  if (tid < 11) {
    float s = 0.f;
    #pragma unroll
    for (int g2 = 0; g2 < 23; g2++) s += red[g2][tid];
    if (tid == 0) h->den[c] = s;
    else h->num[c * 10 + tid - 1] = s;
  }
  __shared__ int sdone;
  __syncthreads();
  __threadfence();
  if (tid == 0) {
    int old = atomicAdd(ticket, 1);
    sdone = (old == NC - 1) ? 1 : 0;
  }
  __syncthreads();
  if (!sdone) return;
  __threadfence();
  __shared__ int sbest;
  if (tid < 12 * SL) { h->r1s[tid] = 0.f; h->r1bs[tid] = 0.f; }
  if (tid == 0) {
    float best = -1.f; int bi = 0;
    for (int cc = 0; cc < NC; cc++) {
      float s = 0.f;
      for (int j = 0; j < 10; j++) { float n = h->num[cc * 10 + j]; s += n * n; }
      float v = s / (h->den[cc] * 10.f);
      if (v > best) { best = v; bi = cc; }
    }
    h->best = bi;
    h->bsel = brk[bi];
    outB[k] = h->bsel;
    sbest = bi;
  }
  __syncthreads();
  int best = sbest;
  for (int d = tid; d < D_IN; d += 256) {
    float v = Wr[(size_t)d * NCP + best];
    wcol[d] = v;
    outW[d * 12 + k] = v;
  }
}

// ---- hc for all rows: one wave per row, float4 loads ----
__global__ __launch_bounds__(256) void k_hc(const float* __restrict__ X,
    const Hdr* __restrict__ h, const float* __restrict__ wcol,
    float* __restrict__ H, float* __restrict__ hc, int k) {
  int lane = threadIdx.x & 63;
  int row = blockIdx.x * 4 + (threadIdx.x >> 6);
  if (row >= N_ROWS) return;
  const float4* xp = (const float4*)(X + (size_t)row * D_IN);
  const float4* wp = (const float4*)wcol;
  float acc = 0.f;
  #pragma unroll
  for (int it = 0; it < 4; it++) {
    int p = lane + it * 64;
    if (p < 196) {
      float4 xv = xp[p], wv = wp[p];
      acc += xv.x * wv.x + xv.y * wv.y + xv.z * wv.z + xv.w * wv.w;
    }
  }
  #pragma unroll
  for (int o = 32; o > 0; o >>= 1) acc += __shfl_xor(acc, o, 64);
  if (lane == 0) {
    float hv = 1.f / (1.f + expf(-(acc + h->bsel)));
    H[(size_t)row * 12 + k] = hv;
    hc[row] = hv;
  }
}

// ---- T^T vec (unnormalized Q columns) with SL-way row-slice split ----
__global__ __launch_bounds__(256) void k_dotQ(const float* __restrict__ Tcm,
    const float* __restrict__ vec, float* __restrict__ dst) {
  int j = blockIdx.x / SL, sl = blockIdx.x % SL;
  const float* q = Tcm + (size_t)j * N_ROWS;
  int i0 = sl * (N_ROWS / SL);
  int i1 = i0 + (N_ROWS / SL);
  float a = 0.f;
  for (int i = i0 + threadIdx.x; i < i1; i += 256) a += q[i] * vec[i];
  __shared__ float red[256];
  red[threadIdx.x] = a;
  __syncthreads();
  for (int s = 128; s > 0; s >>= 1) {
    if (threadIdx.x < s) red[threadIdx.x] += red[threadIdx.x + s];
    __syncthreads();
  }
  if (threadIdx.x == 0) dst[j * SL + sl] = red[0];
}

// ---- t = basev - T cf (cf = raw/(r2_j^2)); writes T[:,k]; partials of t^2, t·Y_j;
//      dofin: last block assembles r2, QT row, R col, backsub (118 blocks) ----
__global__ __launch_bounds__(256) void k_sub_fin(Hdr* h, float* __restrict__ Tcm,
    const float* __restrict__ basev, const float* __restrict__ coefp,
    const float* __restrict__ Y, float* __restrict__ partials,
    float* __restrict__ out_beta, int* __restrict__ ticket, int k, int dofin) {
  __shared__ float cf[12];
  int tid = threadIdx.x;
  if (tid < 12) {
    float s = 0.f;
    #pragma unroll
    for (int s8 = 0; s8 < SL; s8++) s += coefp[tid * SL + s8];
    float r2j = (tid < k) ? h->r2arr[tid] : 1.f;
    cf[tid] = s / (r2j * r2j);
  }
  __syncthreads();
  int i = blockIdx.x * 256 + tid;
  float t = 0.f;
  float v[11];
  #pragma unroll
  for (int q = 0; q < 11; q++) v[q] = 0.f;
  if (i < N_ROWS) {
    t = basev[i];
    for (int j = 0; j < k; j++) t -= Tcm[(size_t)j * N_ROWS + i] * cf[j];
    Tcm[(size_t)k * N_ROWS + i] = t;
    if (dofin) {
      const float* yr = Y + (size_t)i * 10;
      #pragma unroll
      for (int q = 0; q < 10; q++) v[q] = t * yr[q];
      v[10] = t * t;
    }
  }
  if (!dofin) return;
  #pragma unroll
  for (int o = 1; o < 64; o <<= 1) {
    #pragma unroll
    for (int q = 0; q < 11; q++) v[q] += __shfl_xor(v[q], o, 64);
  }
  __shared__ float wred[4][11];
  int wave = tid >> 6, lane = tid & 63;
  if (lane == 0) {
    #pragma unroll
    for (int q = 0; q < 11; q++) wred[wave][q] = v[q];
  }
  __syncthreads();
  if (tid < 11) {
    float s = wred[0][tid] + wred[1][tid] + wred[2][tid] + wred[3][tid];
    partials[blockIdx.x * 12 + tid] = s;
  }
  // ---- last-block finalize ----
  __shared__ int sdone;
  __syncthreads();
  __threadfence();
  if (tid == 0) {
    int old = atomicAdd(ticket, 1);
    sdone = (old == SORT_BLOCKS - 1) ? 1 : 0;
  }
  __syncthreads();
  if (!sdone) return;
  __threadfence();
  __shared__ float red[23][11];
  int q = tid % 11, g = tid / 11;
  float acc2 = 0.f;
  if (tid < 253) {
    for (int b = g; b < SORT_BLOCKS; b += 23)
      acc2 += partials[b * 12 + q];
  }
  if (tid < 253) red[g][q] = acc2;
  __syncthreads();
  __shared__ float s[11];
  __shared__ float Rcol[12];
  __shared__ float r2s;
  if (tid < 11) {
    float ss = 0.f;
    #pragma unroll
    for (int g2 = 0; g2 < 23; g2++) ss += red[g2][tid];
    s[tid] = ss;
  }
  __syncthreads();
  if (tid == 0) {
    float r2 = sqrtf(s[10]);
    h->r2arr[k] = r2;
    h->R[k * 12 + k] = r2;
    r2s = r2;
    Rcol[k] = r2;
    for (int i2 = 0; i2 < k; i2++) {
      float rs = 0.f;
      #pragma unroll
      for (int s8 = 0; s8 < SL; s8++) rs += h->r1s[i2 * SL + s8] + h->r1bs[i2 * SL + s8];
      float Rik = rs / h->r2arr[i2];
      h->R[i2 * 12 + k] = Rik;
      Rcol[i2] = Rik;
    }
  }
  __syncthreads();
  if (tid < 10) {
    float qtk = s[tid] / r2s;
    h->QT[k * 10 + tid] = qtk;
    float bloc[12];
    for (int i2 = k; i2 >= 0; i2--) {
      float t2 = (i2 == k) ? qtk : h->QT[i2 * 10 + tid];
      for (int m = i2 + 1; m <= k; m++) {
        float Rim = (m == k) ? Rcol[i2] : h->R[i2 * 12 + m];
        t2 -= Rim * bloc[m];
      }
      t2 /= ((i2 == k) ? r2s : h->R[i2 * 12 + i2]);
      bloc[i2] = t2;
      h->beta[i2 * 10 + tid] = t2;
      out_beta[i2 * 10 + tid] = t2;
    }
  }
}

static inline int cdiv(int a, int b) { return (a + b - 1) / b; }

extern "C" void kernel_launch(void* const* d_in, const int* in_sizes, int n_in,
                              void* d_out, int out_size, void* d_ws, size_t ws_size,
                              hipStream_t stream) {
  const float* X = (const float*)d_in[0];
  const float* Y = (const float*)d_in[1];
  float* out = (float*)d_out;
  float* outW = out;             // 784*12
  float* outB = out + 9408;      // 12
  float* outBeta = out + 9420;   // 12*10

  char* base = (char*)d_ws;
  Hdr* hdr = (Hdr*)base;
  float* r1p  = (float*)(base + offsetof(Hdr, r1s));
  float* r1bp = (float*)(base + offsetof(Hdr, r1bs));

  size_t off = 16384;
  auto nxt = [&](size_t bytes) -> void* {
    void* p = base + off;
    off += (bytes + 255) & ~(size_t)255;
    return p;
  };
  int* tickets = (int*)nxt(1024);   // [0..11] score, [32..43] subfin
  uint32_t* keysA = (uint32_t*)nxt((size_t)NSEG * SEG * 4);
  uint32_t* keysB = (uint32_t*)nxt((size_t)NSEG * SEG * 4);
  int* valsA = (int*)nxt((size_t)NSEG * SEG * 4);
  int* valsB = (int*)nxt((size_t)NSEG * SEG * 4);
  uint32_t* hs = (uint32_t*)nxt((size_t)NSEG * SORT_BLOCKS * 256 * 4);
  uint32_t* baseA = (uint32_t*)nxt((size_t)NSEG * 256 * 4);
  float* WrAll = (float*)nxt((size_t)NSEG * D_IN * NCP * 4);
  short* WthiAll = (short*)nxt((size_t)NSEG * NCP * KP * 2);
  short* WtloAll = (short*)nxt((size_t)NSEG * NCP * KP * 2);
  float* brAll = (float*)nxt((size_t)NSEG * NC * 4);
  float* wcol = (float*)nxt((size_t)D_IN * 4);
  float* Pbuf = (float*)nxt((size_t)MAXBLK * 1100 * 4);
  float* Tcm = (float*)nxt((size_t)12 * N_ROWS * 4);
  float* Hbuf = (float*)nxt((size_t)N_ROWS * 12 * 4);
  float* hcbuf = (float*)nxt((size_t)N_ROWS * 4);
  float* partials = (float*)nxt(128 * 12 * 4);
  short* Xhi = (short*)nxt((size_t)N_ROWS * KP * 2);
  short* Xlo = (short*)nxt((size_t)N_ROWS * KP * 2);

  hipMemsetAsync(tickets, 0, 1024, stream);

  // 1. RNG key chain + X pre-split
  k_rng_chain<<<1, 64, 0, stream>>>(hdr);
  k_splitX<<<cdiv(N_ROWS * (KP / 8), 256), 256, 0, stream>>>(X, Xhi, Xlo);

  // 2. permutations: 2 rounds x 4 radix passes (keygen fused into pass-0 hist only)
  const int sortgrid = NSEG * SORT_BLOCKS;
  for (int round = 0; round < 2; round++) {
    k_keys_hist<<<sortgrid, 256, 0, stream>>>(hdr, keysA, valsA, hs, round);
    k_scan<<<NSEG, 256, 0, stream>>>(hs, baseA);
    k_scatter<<<sortgrid, 256, 0, stream>>>(keysA, valsA, keysB, valsB, hs, baseA, 0);
    for (int pass = 1; pass < 4; pass++) {
      uint32_t* ik = (pass & 1) ? keysB : keysA;
      uint32_t* ok = (pass & 1) ? keysA : keysB;
      int* iv = (pass & 1) ? valsB : valsA;
      int* ov = (pass & 1) ? valsA : valsB;
      k_hist<<<sortgrid, 256, 0, stream>>>(ik, hs, 8 * pass);
      k_scan<<<NSEG, 256, 0, stream>>>(hs, baseA);
      k_scatter<<<sortgrid, 256, 0, stream>>>(ik, iv, ok, ov, hs, baseA, 8 * pass);
    }
  }

  // 3. candidate weights (fp32 + transposed bf16 hi/lo + biases, one kernel)
  k_gen<<<cdiv(NSEG * NCP * KP, 256), 256, 0, stream>>>(hdr, WrAll, WthiAll, WtloAll, brAll);

  // 4. sequential training loop
  for (int k = 0; k < 12; k++) {
    int bs = 4000 + 2166 * k;
    int nblk = cdiv(bs, 64);
    const int* perm = valsA + (size_t)k * SEG;
    const short* Wthi = WthiAll + (size_t)k * NCP * KP;
    const short* Wtlo = WtloAll + (size_t)k * NCP * KP;
    const float* brk = brAll + (size_t)k * NC;

    k_batch_mfma<<<nblk, 256, 0, stream>>>(Xhi, Xlo, Wthi, Wtlo, brk, perm, Y, Hbuf, hdr, Pbuf, k, bs);
    k_score_select<<<NC, 256, 0, stream>>>(Pbuf, hdr, brk,
        WrAll + (size_t)k * D_IN * NCP, wcol, outW, outB, &tickets[k], k, nblk);
    k_hc<<<7500, 256, 0, stream>>>(X, hdr, wcol, Hbuf, hcbuf, k);
    if (k > 0) k_dotQ<<<k * SL, 256, 0, stream>>>(Tcm, hcbuf, r1p);
    if (k == 1 || k == 2) {
      // reorthogonalize (emulates inv/Householder branches): pass1 no-fin
      k_sub_fin<<<SORT_BLOCKS, 256, 0, stream>>>(hdr, Tcm, hcbuf, r1p, Y, partials,
          outBeta, &tickets[32 + k], k, 0);
      k_dotQ<<<k * SL, 256, 0, stream>>>(Tcm, Tcm + (size_t)k * N_ROWS, r1bp);
      k_sub_fin<<<SORT_BLOCKS, 256, 0, stream>>>(hdr, Tcm, Tcm + (size_t)k * N_ROWS, r1bp,
          Y, partials, outBeta, &tickets[32 + k], k, 1);
    } else {
      k_sub_fin<<<SORT_BLOCKS, 256, 0, stream>>>(hdr, Tcm, hcbuf, r1p, Y, partials,
          outBeta, &tickets[32 + k], k, 1);
    }
  }
}

// Round 12
// 1662.705 us; speedup vs baseline: 1.1584x; 1.1584x over previous
//
#include <hip/hip_runtime.h>
#include <cstdint>
#include <cstddef>
#include <cmath>

#define N_ROWS 30000
#define D_IN   784
#define NC     100
#define NCP    128
#define NSEG   12
#define SEG    30000
#define SORT_BLOCKS 118   // ceil(30000/256)
#define KP     800        // K padded to multiple of 32
#define TR     32         // rows per block in batch GEMM
#define MAXBLK 870        // ceil(27826/32)
#define SL     16         // row-slices for k_dotQ

typedef short bf16x8 __attribute__((ext_vector_type(8)));
typedef float f32x4  __attribute__((ext_vector_type(4)));

struct Hdr {
  uint32_t kperm[12][2];
  uint32_t kw[12][2];
  uint32_t kb[12][2];
  uint32_t sub[12][2][2];
  int best; int pad0;
  float bsel;
  float r2arr[12];       // column norms of unnormalized Q columns
  float r1s[12 * SL];    // Q^T hc raw partials, SL slices per j
  float r1bs[12 * SL];   // reorth raw partials
  float R[144];      // 12x12 row-major
  float QT[120];     // 12x10
  float beta[120];   // 12x10
  float den[100];
  float num[1000];   // [c][j]
};

__device__ __forceinline__ void tf2x32(uint32_t k0, uint32_t k1,
                                       uint32_t x0, uint32_t x1,
                                       uint32_t& o0, uint32_t& o1) {
  const uint32_t kx = k0 ^ k1 ^ 0x1BD11BDAu;
  x0 += k0; x1 += k1;
  x0 += x1; x1 = (x1<<13)|(x1>>19); x1 ^= x0;
  x0 += x1; x1 = (x1<<15)|(x1>>17); x1 ^= x0;
  x0 += x1; x1 = (x1<<26)|(x1>>6);  x1 ^= x0;
  x0 += x1; x1 = (x1<<6) |(x1>>26); x1 ^= x0;
  x0 += k1; x1 += kx + 1u;
  x0 += x1; x1 = (x1<<17)|(x1>>15); x1 ^= x0;
  x0 += x1; x1 = (x1<<29)|(x1>>3);  x1 ^= x0;
  x0 += x1; x1 = (x1<<16)|(x1>>16); x1 ^= x0;
  x0 += x1; x1 = (x1<<24)|(x1>>8);  x1 ^= x0;
  x0 += kx; x1 += k0 + 2u;
  x0 += x1; x1 = (x1<<13)|(x1>>19); x1 ^= x0;
  x0 += x1; x1 = (x1<<15)|(x1>>17); x1 ^= x0;
  x0 += x1; x1 = (x1<<26)|(x1>>6);  x1 ^= x0;
  x0 += x1; x1 = (x1<<6) |(x1>>26); x1 ^= x0;
  x0 += k0; x1 += k1 + 3u;
  x0 += x1; x1 = (x1<<17)|(x1>>15); x1 ^= x0;
  x0 += x1; x1 = (x1<<29)|(x1>>3);  x1 ^= x0;
  x0 += x1; x1 = (x1<<16)|(x1>>16); x1 ^= x0;
  x0 += x1; x1 = (x1<<24)|(x1>>8);  x1 ^= x0;
  x0 += k1; x1 += kx + 4u;
  x0 += x1; x1 = (x1<<13)|(x1>>19); x1 ^= x0;
  x0 += x1; x1 = (x1<<15)|(x1>>17); x1 ^= x0;
  x0 += x1; x1 = (x1<<26)|(x1>>6);  x1 ^= x0;
  x0 += x1; x1 = (x1<<6) |(x1>>26); x1 ^= x0;
  x0 += kx; x1 += k0 + 5u;
  o0 = x0; o1 = x1;
}

__device__ __forceinline__ float u01(uint32_t bits) {
  return __uint_as_float((bits >> 9) | 0x3f800000u) - 1.0f;
}

__device__ __forceinline__ uint32_t rbits32(uint32_t k0, uint32_t k1, uint32_t idx) {
  uint32_t o0, o1;
  tf2x32(k0, k1, 0u, idx, o0, o1);
  return o0 ^ o1;
}

__device__ __forceinline__ ushort f2bf_rne(float f) {
  uint32_t u = __float_as_uint(f);
  return (ushort)((u + 0x7fffu + ((u >> 16) & 1u)) >> 16);
}
__device__ __forceinline__ float bf2f(ushort h) {
  return __uint_as_float(((uint32_t)h) << 16);
}

// ---------------- RNG key chain (jax_threefry_partitionable=True) ----------------
__global__ void k_rng_chain(Hdr* h) {
  if (threadIdx.x != 0 || blockIdx.x != 0) return;
  uint32_t c0 = 0u, c1 = 42u;
  for (int k = 0; k < 12; k++) {
    uint32_t t0, t1;
    tf2x32(c0, c1, 0u, 1u, t0, t1); h->kperm[k][0] = t0; h->kperm[k][1] = t1;
    tf2x32(c0, c1, 0u, 2u, t0, t1); h->kw[k][0]   = t0; h->kw[k][1]   = t1;
    tf2x32(c0, c1, 0u, 3u, t0, t1); h->kb[k][0]   = t0; h->kb[k][1]   = t1;
    uint32_t p0 = h->kperm[k][0], p1 = h->kperm[k][1];
    for (int r = 0; r < 2; r++) {
      uint32_t s0, s1, n0, n1;
      tf2x32(p0, p1, 0u, 1u, s0, s1);
      tf2x32(p0, p1, 0u, 0u, n0, n1);
      h->sub[k][r][0] = s0; h->sub[k][r][1] = s1;
      p0 = n0; p1 = n1;
    }
    tf2x32(c0, c1, 0u, 0u, t0, t1); c0 = t0; c1 = t1;
  }
}

// ---------------- X pre-split to bf16 hi/lo, KP-padded ----------------
__global__ __launch_bounds__(256) void k_splitX(const float* __restrict__ X,
    short* __restrict__ Xhi, short* __restrict__ Xlo) {
  int t = blockIdx.x * 256 + threadIdx.x;       // one thread per 8-elem group
  if (t >= N_ROWS * (KP / 8)) return;
  int i = t / (KP / 8), g = t % (KP / 8);
  int kb = g * 8;
  float v[8];
  if (kb + 8 <= D_IN) {
    const float* xr = X + (size_t)i * D_IN + kb;
    float4 p0 = *(const float4*)xr;
    float4 p1 = *(const float4*)(xr + 4);
    v[0]=p0.x; v[1]=p0.y; v[2]=p0.z; v[3]=p0.w;
    v[4]=p1.x; v[5]=p1.y; v[6]=p1.z; v[7]=p1.w;
  } else {
    #pragma unroll
    for (int q = 0; q < 8; q++) v[q] = 0.f;
  }
  uint32_t ph[4], pl[4];
  #pragma unroll
  for (int q = 0; q < 4; q++) {
    ushort h0 = f2bf_rne(v[2*q]),   h1 = f2bf_rne(v[2*q+1]);
    ushort l0 = f2bf_rne(v[2*q]   - bf2f(h0));
    ushort l1 = f2bf_rne(v[2*q+1] - bf2f(h1));
    ph[q] = (uint32_t)h0 | ((uint32_t)h1 << 16);
    pl[q] = (uint32_t)l0 | ((uint32_t)l1 << 16);
  }
  size_t o = (size_t)i * KP + kb;
  *(uint4*)(Xhi + o) = make_uint4(ph[0], ph[1], ph[2], ph[3]);
  *(uint4*)(Xlo + o) = make_uint4(pl[0], pl[1], pl[2], pl[3]);
}

// ---------------- radix sort (separate hist/scan/scatter) ----------------
__global__ __launch_bounds__(256) void k_keys_hist(const Hdr* __restrict__ h,
    uint32_t* __restrict__ keys, int* __restrict__ vals,
    uint32_t* __restrict__ hs, int round) {
  __shared__ uint32_t hloc[256];
  int s = blockIdx.x / SORT_BLOCKS, b = blockIdx.x % SORT_BLOCKS;
  int tid = threadIdx.x;
  hloc[tid] = 0;
  __syncthreads();
  int i = b * 256 + tid;
  if (i < SEG) {
    uint32_t key = rbits32(h->sub[s][round][0], h->sub[s][round][1], (uint32_t)i);
    keys[s * SEG + i] = key;
    if (round == 0) vals[s * SEG + i] = i;
    atomicAdd(&hloc[key & 255u], 1u);
  }
  __syncthreads();
  hs[(size_t)(s * SORT_BLOCKS + b) * 256 + tid] = hloc[tid];
}

__global__ __launch_bounds__(256) void k_hist(const uint32_t* __restrict__ keys,
    uint32_t* __restrict__ hs, int shift) {
  __shared__ uint32_t hloc[256];
  int s = blockIdx.x / SORT_BLOCKS, b = blockIdx.x % SORT_BLOCKS;
  hloc[threadIdx.x] = 0;
  __syncthreads();
  int i = b * 256 + threadIdx.x;
  if (i < SEG) {
    uint32_t d = (keys[s * SEG + i] >> shift) & 255u;
    atomicAdd(&hloc[d], 1u);
  }
  __syncthreads();
  hs[(size_t)(s * SORT_BLOCKS + b) * 256 + threadIdx.x] = hloc[threadIdx.x];
}

// chunked pipelined scan; per-(s,block) local offsets + per-(s,digit) base
__global__ __launch_bounds__(256) void k_scan(uint32_t* hs, uint32_t* baseA) {
  __shared__ uint32_t tot[256];
  __shared__ uint32_t base[256];
  int s = blockIdx.x, d = threadIdx.x;
  uint32_t run = 0;
  uint32_t buf[30];
  for (int c0 = 0; c0 < SORT_BLOCKS; c0 += 30) {
    int n = SORT_BLOCKS - c0; if (n > 30) n = 30;
    #pragma unroll
    for (int j = 0; j < 30; j++)
      if (j < n) buf[j] = hs[(size_t)(s * SORT_BLOCKS + c0 + j) * 256 + d];
    #pragma unroll
    for (int j = 0; j < 30; j++)
      if (j < n) {
        uint32_t c = buf[j];
        hs[(size_t)(s * SORT_BLOCKS + c0 + j) * 256 + d] = run;
        run += c;
      }
  }
  tot[d] = run;
  __syncthreads();
  if (d == 0) {
    uint32_t acc = 0;
    for (int q = 0; q < 256; q++) { base[q] = acc; acc += tot[q]; }
  }
  __syncthreads();
  baseA[s * 256 + d] = base[d];
}

__global__ __launch_bounds__(256) void k_scatter(const uint32_t* __restrict__ ik,
    const int* __restrict__ iv, uint32_t* __restrict__ ok, int* __restrict__ ov,
    const uint32_t* __restrict__ hs, const uint32_t* __restrict__ baseA, int shift) {
  __shared__ uint16_t wh[4][256];
  int s = blockIdx.x / SORT_BLOCKS, b = blockIdx.x % SORT_BLOCKS;
  int tid = threadIdx.x;
  for (int q = tid; q < 1024; q += 256) ((uint16_t*)wh)[q] = 0;
  __syncthreads();
  int i = b * 256 + tid;
  bool valid = (i < SEG);
  uint32_t key = 0, dg = 0; int val = 0;
  if (valid) {
    key = ik[s * SEG + i];
    val = iv[s * SEG + i];
    dg = (key >> shift) & 255u;
  }
  unsigned long long vm = __ballot(valid ? 1 : 0);
  unsigned long long m = ~0ULL;
  for (int bit = 0; bit < 8; bit++) {
    unsigned long long bm = __ballot((int)((dg >> bit) & 1u));
    m &= ((dg >> bit) & 1u) ? bm : ~bm;
  }
  m &= vm;
  int wv = tid >> 6, lane = tid & 63;
  int rw = __popcll(m & ((1ULL << lane) - 1ULL));
  if (valid && rw == 0) wh[wv][dg] = (uint16_t)__popcll(m);
  __syncthreads();
  if (valid) {
    int rank = rw;
    for (int q = 0; q < wv; q++) rank += wh[q][dg];
    uint32_t pos = hs[(size_t)(s * SORT_BLOCKS + b) * 256 + dg] + baseA[s * 256 + dg] + rank;
    ok[s * SEG + pos] = key;
    ov[s * SEG + pos] = val;
  }
}

// ---------------- candidate weight generation (W + b fused) ----------------
__global__ __launch_bounds__(256) void k_gen(const Hdr* __restrict__ h,
    float* __restrict__ Wr, short* __restrict__ Wthi, short* __restrict__ Wtlo,
    float* __restrict__ br) {
  int t = blockIdx.x * 256 + threadIdx.x;
  if (t >= NSEG * NCP * KP) return;
  if (t < NSEG * NC) {
    int k = t / NC, c = t % NC;
    float u = u01(rbits32(h->kb[k][0], h->kb[k][1], (uint32_t)c));
    float lam = (c < 50) ? 1.f : 10.f;
    br[t] = lam * (2.f * u - 1.f);
  }
  int seg = t / (NCP * KP);
  int r = t % (NCP * KP);
  int c = r / KP, d = r % KP;
  float val = 0.f;
  if (c < NC && d < D_IN) {
    int n = d * NC + c;  // row-major linear index of (784,100)
    float u = u01(rbits32(h->kw[seg][0], h->kw[seg][1], (uint32_t)n));
    float lam = (c < 50) ? 1.f : 10.f;
    val = lam * (2.f * u - 1.f);
  }
  ushort hi = f2bf_rne(val);
  ushort lo = f2bf_rne(val - bf2f(hi));
  Wthi[t] = (short)hi;
  Wtlo[t] = (short)lo;
  if (d < D_IN) Wr[(size_t)seg * D_IN * NCP + (size_t)d * NCP + c] = val;
}

// ---- MFMA split-bf16 candidate GEMM; LDS-staged (coalesced), 32-row tile ----
// block: TR=32 gathered rows x 128 cols; 4 waves; wave w owns n-tiles {2w,2w+1}, m-tiles 0..1
__global__ __launch_bounds__(256) void k_batch_mfma(const short* __restrict__ Xhi,
    const short* __restrict__ Xlo,
    const short* __restrict__ Wthi, const short* __restrict__ Wtlo,
    const float* __restrict__ br, const int* __restrict__ perm,
    const float* __restrict__ Y, const float* __restrict__ Hbuf,
    const Hdr* __restrict__ hd, float* __restrict__ P, int kk, int bs) {
  __shared__ short Ah[TR][40], Al[TR][40];    // 80B row stride
  __shared__ short Bh[128][40], Bl[128][40];
  __shared__ int idxs[TR];
  __shared__ float ekS[TR][10];
  __shared__ float hS[TR][12];
  __shared__ float betaS[120];
  int tid = threadIdx.x;
  int row0 = blockIdx.x * TR;
  if (tid < TR) {
    int rr = row0 + tid;
    idxs[tid] = perm[rr < bs ? rr : (bs - 1)];
  }
  if (kk > 0 && tid < kk * 10) betaS[tid] = hd->beta[tid];
  __syncthreads();
  if (kk > 0) {
    for (int q = tid; q < TR * kk; q += 256) {
      int r = q / kk, m = q % kk;
      hS[r][m] = Hbuf[(size_t)idxs[r] * 12 + m];
    }
  }
  __syncthreads();
  for (int q = tid; q < TR * 10; q += 256) {
    int r = q / 10, j = q % 10;
    float e = 0.f;
    if (row0 + r < bs) {
      e = Y[(size_t)idxs[r] * 10 + j];
      if (kk > 0) {
        float yv = 0.f;
        for (int m = 0; m < kk; m++) yv += hS[r][m] * betaS[m * 10 + j];
        e -= yv;
      }
    }
    ekS[r][j] = e;
  }
  int wave = tid >> 6, lane = tid & 63;
  int kg = lane >> 4, ln = lane & 15;

  f32x4 acc[2][2];
  #pragma unroll
  for (int m = 0; m < 2; m++)
    #pragma unroll
    for (int j = 0; j < 2; j++)
      acc[m][j] = (f32x4){0.f, 0.f, 0.f, 0.f};

  // A staging map: 256 threads = 32 rows x {hi,lo} x 4 chunks (one uint4 each)
  int ar = tid >> 3;           // 0..31
  int asub = tid & 7;          // 0..7
  int aq = asub & 3;           // chunk
  bool alo = asub >= 4;
  // B staging map: 2 threads per col, 16-short halves, both arrays
  int bcol = tid >> 1, bh2 = tid & 1;

  for (int k0 = 0; k0 < KP; k0 += 32) {
    __syncthreads();
    {  // stage A (coalesced copy of pre-split Xhi/Xlo)
      size_t o = (size_t)idxs[ar] * KP + k0 + aq * 8;
      const short* src = alo ? Xlo : Xhi;
      short (*dst)[40] = alo ? Al : Ah;
      *(uint4*)&dst[ar][aq * 8] = *(const uint4*)(src + o);
    }
    {  // stage B
      int boff = bh2 * 16;
      const uint4* sh = (const uint4*)(Wthi + (size_t)bcol * KP + k0 + boff);
      const uint4* sl = (const uint4*)(Wtlo + (size_t)bcol * KP + k0 + boff);
      uint4 h0 = sh[0], h1 = sh[1], l0 = sl[0], l1 = sl[1];
      *(uint4*)&Bh[bcol][boff]     = h0;
      *(uint4*)&Bh[bcol][boff + 8] = h1;
      *(uint4*)&Bl[bcol][boff]     = l0;
      *(uint4*)&Bl[bcol][boff + 8] = l1;
    }
    __syncthreads();
    bf16x8 bhf[2], blf[2];
    #pragma unroll
    for (int j = 0; j < 2; j++) {
      int n = (2 * wave + j) * 16 + ln;
      bhf[j] = *(bf16x8*)&Bh[n][kg * 8];
      blf[j] = *(bf16x8*)&Bl[n][kg * 8];
    }
    #pragma unroll
    for (int m = 0; m < 2; m++) {
      bf16x8 ah = *(bf16x8*)&Ah[m * 16 + ln][kg * 8];
      bf16x8 al = *(bf16x8*)&Al[m * 16 + ln][kg * 8];
      #pragma unroll
      for (int j = 0; j < 2; j++) {
        acc[m][j] = __builtin_amdgcn_mfma_f32_16x16x32_bf16(ah, bhf[j], acc[m][j], 0, 0, 0);
        acc[m][j] = __builtin_amdgcn_mfma_f32_16x16x32_bf16(ah, blf[j], acc[m][j], 0, 0, 0);
        acc[m][j] = __builtin_amdgcn_mfma_f32_16x16x32_bf16(al, bhf[j], acc[m][j], 0, 0, 0);
      }
    }
  }
  // ---- fused epilogue: sigmoid + den/num partials, plain stores to P ----
  // C/D layout: col=lane&15, row=(lane>>4)*4+reg. Lanes kg=0..3 share a column.
  #pragma unroll
  for (int j = 0; j < 2; j++) {
    int col = (2 * wave + j) * 16 + ln;
    float bias = (col < NC) ? br[col] : 0.f;
    float den_t = 0.f;
    float num_t[10];
    #pragma unroll
    for (int q = 0; q < 10; q++) num_t[q] = 0.f;
    #pragma unroll
    for (int m = 0; m < 2; m++) {
      #pragma unroll
      for (int r = 0; r < 4; r++) {
        int rl = m * 16 + kg * 4 + r;
        if (row0 + rl < bs) {
          float hsig = 1.f / (1.f + expf(-(acc[m][j][r] + bias)));
          den_t += hsig * hsig;
          #pragma unroll
          for (int q = 0; q < 10; q++) num_t[q] += hsig * ekS[rl][q];
        }
      }
    }
    den_t += __shfl_xor(den_t, 16, 64);
    den_t += __shfl_xor(den_t, 32, 64);
    #pragma unroll
    for (int q = 0; q < 10; q++) {
      num_t[q] += __shfl_xor(num_t[q], 16, 64);
      num_t[q] += __shfl_xor(num_t[q], 32, 64);
    }
    if (kg == 0 && col < NC) {
      float* dst = P + (size_t)blockIdx.x * 1100 + col * 11;
      dst[0] = den_t;
      #pragma unroll
      for (int q = 0; q < 10; q++) dst[1 + q] = num_t[q];
    }
  }
}

// ---- score reduce + select + wcol (merged via last-block ticket, 100 blocks) ----
__global__ __launch_bounds__(256) void k_score_select(const float* __restrict__ P,
    Hdr* h, const float* __restrict__ brk, const float* __restrict__ Wr,
    float* __restrict__ wcol, float* __restrict__ outW, float* __restrict__ outB,
    int* __restrict__ ticket, int k, int nblk) {
  int c = blockIdx.x;           // 0..99
  int tid = threadIdx.x;
  int q = tid % 11, g = tid / 11;   // 23 groups of 11
  float acc = 0.f;
  if (tid < 253) {
    for (int b = g; b < nblk; b += 23)
      acc += P[(size_t)b * 1100 + c * 11 + q];
  }
  __shared__ float red[23][11];
  if (tid < 253) red[g][q] = acc;
  __syncthreads();
  if (tid < 11) {
    float s = 0.f;
    #pragma unroll
    for (int g2 = 0; g2 < 23; g2++) s += red[g2][tid];
    if (tid == 0) h->den[c] = s;
    else h->num[c * 10 + tid - 1] = s;
  }
  __shared__ int sdone;
  __syncthreads();
  __threadfence();
  if (tid == 0) {
    int old = atomicAdd(ticket, 1);
    sdone = (old == NC - 1) ? 1 : 0;
  }
  __syncthreads();
  if (!sdone) return;
  __threadfence();
  __shared__ int sbest;
  if (tid < 12 * SL) { h->r1s[tid] = 0.f; h->r1bs[tid] = 0.f; }
  if (tid == 0) {
    float best = -1.f; int bi = 0;
    for (int cc = 0; cc < NC; cc++) {
      float s = 0.f;
      for (int j = 0; j < 10; j++) { float n = h->num[cc * 10 + j]; s += n * n; }
      float v = s / (h->den[cc] * 10.f);
      if (v > best) { best = v; bi = cc; }
    }
    h->best = bi;
    h->bsel = brk[bi];
    outB[k] = h->bsel;
    sbest = bi;
  }
  __syncthreads();
  int best = sbest;
  for (int d = tid; d < D_IN; d += 256) {
    float v = Wr[(size_t)d * NCP + best];
    wcol[d] = v;
    outW[d * 12 + k] = v;
  }
}

// ---- hc for all rows: one wave per row, float4 loads ----
__global__ __launch_bounds__(256) void k_hc(const float* __restrict__ X,
    const Hdr* __restrict__ h, const float* __restrict__ wcol,
    float* __restrict__ H, float* __restrict__ hc, int k) {
  int lane = threadIdx.x & 63;
  int row = blockIdx.x * 4 + (threadIdx.x >> 6);
  if (row >= N_ROWS) return;
  const float4* xp = (const float4*)(X + (size_t)row * D_IN);
  const float4* wp = (const float4*)wcol;
  float acc = 0.f;
  #pragma unroll
  for (int it = 0; it < 4; it++) {
    int p = lane + it * 64;
    if (p < 196) {
      float4 xv = xp[p], wv = wp[p];
      acc += xv.x * wv.x + xv.y * wv.y + xv.z * wv.z + xv.w * wv.w;
    }
  }
  #pragma unroll
  for (int o = 32; o > 0; o >>= 1) acc += __shfl_xor(acc, o, 64);
  if (lane == 0) {
    float hv = 1.f / (1.f + expf(-(acc + h->bsel)));
    H[(size_t)row * 12 + k] = hv;
    hc[row] = hv;
  }
}

// ---- T^T vec (unnormalized Q columns) with SL-way row-slice split ----
__global__ __launch_bounds__(256) void k_dotQ(const float* __restrict__ Tcm,
    const float* __restrict__ vec, float* __restrict__ dst) {
  int j = blockIdx.x / SL, sl = blockIdx.x % SL;
  const float* q = Tcm + (size_t)j * N_ROWS;
  int i0 = sl * (N_ROWS / SL);
  int i1 = i0 + (N_ROWS / SL);
  float a = 0.f;
  for (int i = i0 + threadIdx.x; i < i1; i += 256) a += q[i] * vec[i];
  __shared__ float red[256];
  red[threadIdx.x] = a;
  __syncthreads();
  for (int s = 128; s > 0; s >>= 1) {
    if (threadIdx.x < s) red[threadIdx.x] += red[threadIdx.x + s];
    __syncthreads();
  }
  if (threadIdx.x == 0) dst[j * SL + sl] = red[0];
}

// ---- t = basev - T cf (cf = raw/(r2_j^2)); writes T[:,k]; partials of t^2, t·Y_j;
//      dofin: last block assembles r2, QT row, R col, backsub (118 blocks) ----
__global__ __launch_bounds__(256) void k_sub_fin(Hdr* h, float* __restrict__ Tcm,
    const float* __restrict__ basev, const float* __restrict__ coefp,
    const float* __restrict__ Y, float* __restrict__ partials,
    float* __restrict__ out_beta, int* __restrict__ ticket, int k, int dofin) {
  __shared__ float cf[12];
  int tid = threadIdx.x;
  if (tid < 12) {
    float s = 0.f;
    #pragma unroll
    for (int s8 = 0; s8 < SL; s8++) s += coefp[tid * SL + s8];
    float r2j = (tid < k) ? h->r2arr[tid] : 1.f;
    cf[tid] = s / (r2j * r2j);
  }
  __syncthreads();
  int i = blockIdx.x * 256 + tid;
  float t = 0.f;
  float v[11];
  #pragma unroll
  for (int q = 0; q < 11; q++) v[q] = 0.f;
  if (i < N_ROWS) {
    t = basev[i];
    for (int j = 0; j < k; j++) t -= Tcm[(size_t)j * N_ROWS + i] * cf[j];
    Tcm[(size_t)k * N_ROWS + i] = t;
    if (dofin) {
      const float* yr = Y + (size_t)i * 10;
      #pragma unroll
      for (int q = 0; q < 10; q++) v[q] = t * yr[q];
      v[10] = t * t;
    }
  }
  if (!dofin) return;
  #pragma unroll
  for (int o = 1; o < 64; o <<= 1) {
    #pragma unroll
    for (int q = 0; q < 11; q++) v[q] += __shfl_xor(v[q], o, 64);
  }
  __shared__ float wred[4][11];
  int wave = tid >> 6, lane = tid & 63;
  if (lane == 0) {
    #pragma unroll
    for (int q = 0; q < 11; q++) wred[wave][q] = v[q];
  }
  __syncthreads();
  if (tid < 11) {
    float s = wred[0][tid] + wred[1][tid] + wred[2][tid] + wred[3][tid];
    partials[blockIdx.x * 12 + tid] = s;
  }
  // ---- last-block finalize ----
  __shared__ int sdone;
  __syncthreads();
  __threadfence();
  if (tid == 0) {
    int old = atomicAdd(ticket, 1);
    sdone = (old == SORT_BLOCKS - 1) ? 1 : 0;
  }
  __syncthreads();
  if (!sdone) return;
  __threadfence();
  __shared__ float red[23][11];
  int q = tid % 11, g = tid / 11;
  float acc2 = 0.f;
  if (tid < 253) {
    for (int b = g; b < SORT_BLOCKS; b += 23)
      acc2 += partials[b * 12 + q];
  }
  if (tid < 253) red[g][q] = acc2;
  __syncthreads();
  __shared__ float s[11];
  __shared__ float Rcol[12];
  __shared__ float r2s;
  if (tid < 11) {
    float ss = 0.f;
    #pragma unroll
    for (int g2 = 0; g2 < 23; g2++) ss += red[g2][tid];
    s[tid] = ss;
  }
  __syncthreads();
  if (tid == 0) {
    float r2 = sqrtf(s[10]);
    h->r2arr[k] = r2;
    h->R[k * 12 + k] = r2;
    r2s = r2;
    Rcol[k] = r2;
    for (int i2 = 0; i2 < k; i2++) {
      float rs = 0.f;
      #pragma unroll
      for (int s8 = 0; s8 < SL; s8++) rs += h->r1s[i2 * SL + s8] + h->r1bs[i2 * SL + s8];
      float Rik = rs / h->r2arr[i2];
      h->R[i2 * 12 + k] = Rik;
      Rcol[i2] = Rik;
    }
  }
  __syncthreads();
  if (tid < 10) {
    float qtk = s[tid] / r2s;
    h->QT[k * 10 + tid] = qtk;
    float bloc[12];
    for (int i2 = k; i2 >= 0; i2--) {
      float t2 = (i2 == k) ? qtk : h->QT[i2 * 10 + tid];
      for (int m = i2 + 1; m <= k; m++) {
        float Rim = (m == k) ? Rcol[i2] : h->R[i2 * 12 + m];
        t2 -= Rim * bloc[m];
      }
      t2 /= ((i2 == k) ? r2s : h->R[i2 * 12 + i2]);
      bloc[i2] = t2;
      h->beta[i2 * 10 + tid] = t2;
      out_beta[i2 * 10 + tid] = t2;
    }
  }
}

static inline int cdiv(int a, int b) { return (a + b - 1) / b; }

extern "C" void kernel_launch(void* const* d_in, const int* in_sizes, int n_in,
                              void* d_out, int out_size, void* d_ws, size_t ws_size,
                              hipStream_t stream) {
  const float* X = (const float*)d_in[0];
  const float* Y = (const float*)d_in[1];
  float* out = (float*)d_out;
  float* outW = out;             // 784*12
  float* outB = out + 9408;      // 12
  float* outBeta = out + 9420;   // 12*10

  char* base = (char*)d_ws;
  Hdr* hdr = (Hdr*)base;
  float* r1p  = (float*)(base + offsetof(Hdr, r1s));
  float* r1bp = (float*)(base + offsetof(Hdr, r1bs));

  size_t off = 16384;
  auto nxt = [&](size_t bytes) -> void* {
    void* p = base + off;
    off += (bytes + 255) & ~(size_t)255;
    return p;
  };
  int* tickets = (int*)nxt(1024);   // [0..11] score, [32..43] subfin
  uint32_t* keysA = (uint32_t*)nxt((size_t)NSEG * SEG * 4);
  uint32_t* keysB = (uint32_t*)nxt((size_t)NSEG * SEG * 4);
  int* valsA = (int*)nxt((size_t)NSEG * SEG * 4);
  int* valsB = (int*)nxt((size_t)NSEG * SEG * 4);
  uint32_t* hs = (uint32_t*)nxt((size_t)NSEG * SORT_BLOCKS * 256 * 4);
  uint32_t* baseA = (uint32_t*)nxt((size_t)NSEG * 256 * 4);
  float* WrAll = (float*)nxt((size_t)NSEG * D_IN * NCP * 4);
  short* WthiAll = (short*)nxt((size_t)NSEG * NCP * KP * 2);
  short* WtloAll = (short*)nxt((size_t)NSEG * NCP * KP * 2);
  float* brAll = (float*)nxt((size_t)NSEG * NC * 4);
  float* wcol = (float*)nxt((size_t)D_IN * 4);
  float* Pbuf = (float*)nxt((size_t)MAXBLK * 1100 * 4);
  float* Tcm = (float*)nxt((size_t)12 * N_ROWS * 4);
  float* Hbuf = (float*)nxt((size_t)N_ROWS * 12 * 4);
  float* hcbuf = (float*)nxt((size_t)N_ROWS * 4);
  float* partials = (float*)nxt(128 * 12 * 4);
  short* Xhi = (short*)nxt((size_t)N_ROWS * KP * 2);
  short* Xlo = (short*)nxt((size_t)N_ROWS * KP * 2);

  hipMemsetAsync(tickets, 0, 1024, stream);

  // 1. RNG key chain + X pre-split
  k_rng_chain<<<1, 64, 0, stream>>>(hdr);
  k_splitX<<<cdiv(N_ROWS * (KP / 8), 256), 256, 0, stream>>>(X, Xhi, Xlo);

  // 2. permutations: 2 rounds x 4 radix passes (keygen fused into pass-0 hist only)
  const int sortgrid = NSEG * SORT_BLOCKS;
  for (int round = 0; round < 2; round++) {
    k_keys_hist<<<sortgrid, 256, 0, stream>>>(hdr, keysA, valsA, hs, round);
    k_scan<<<NSEG, 256, 0, stream>>>(hs, baseA);
    k_scatter<<<sortgrid, 256, 0, stream>>>(keysA, valsA, keysB, valsB, hs, baseA, 0);
    for (int pass = 1; pass < 4; pass++) {
      uint32_t* ik = (pass & 1) ? keysB : keysA;
      uint32_t* ok = (pass & 1) ? keysA : keysB;
      int* iv = (pass & 1) ? valsB : valsA;
      int* ov = (pass & 1) ? valsA : valsB;
      k_hist<<<sortgrid, 256, 0, stream>>>(ik, hs, 8 * pass);
      k_scan<<<NSEG, 256, 0, stream>>>(hs, baseA);
      k_scatter<<<sortgrid, 256, 0, stream>>>(ik, iv, ok, ov, hs, baseA, 8 * pass);
    }
  }

  // 3. candidate weights (fp32 + transposed bf16 hi/lo + biases, one kernel)
  k_gen<<<cdiv(NSEG * NCP * KP, 256), 256, 0, stream>>>(hdr, WrAll, WthiAll, WtloAll, brAll);

  // 4. sequential training loop
  for (int k = 0; k < 12; k++) {
    int bs = 4000 + 2166 * k;
    int nblk = cdiv(bs, TR);
    const int* perm = valsA + (size_t)k * SEG;
    const short* Wthi = WthiAll + (size_t)k * NCP * KP;
    const short* Wtlo = WtloAll + (size_t)k * NCP * KP;
    const float* brk = brAll + (size_t)k * NC;

    k_batch_mfma<<<nblk, 256, 0, stream>>>(Xhi, Xlo, Wthi, Wtlo, brk, perm, Y, Hbuf, hdr, Pbuf, k, bs);
    k_score_select<<<NC, 256, 0, stream>>>(Pbuf, hdr, brk,
        WrAll + (size_t)k * D_IN * NCP, wcol, outW, outB, &tickets[k], k, nblk);
    k_hc<<<7500, 256, 0, stream>>>(X, hdr, wcol, Hbuf, hcbuf, k);
    if (k > 0) k_dotQ<<<k * SL, 256, 0, stream>>>(Tcm, hcbuf, r1p);
    if (k == 1 || k == 2) {
      // reorthogonalize (emulates inv/Householder branches): pass1 no-fin
      k_sub_fin<<<SORT_BLOCKS, 256, 0, stream>>>(hdr, Tcm, hcbuf, r1p, Y, partials,
          outBeta, &tickets[32 + k], k, 0);
      k_dotQ<<<k * SL, 256, 0, stream>>>(Tcm, Tcm + (size_t)k * N_ROWS, r1bp);
      k_sub_fin<<<SORT_BLOCKS, 256, 0, stream>>>(hdr, Tcm, Tcm + (size_t)k * N_ROWS, r1bp,
          Y, partials, outBeta, &tickets[32 + k], k, 1);
    } else {
      k_sub_fin<<<SORT_BLOCKS, 256, 0, stream>>>(hdr, Tcm, hcbuf, r1p, Y, partials,
          outBeta, &tickets[32 + k], k, 1);
    }
  }
}

// Round 13
// 1594.967 us; speedup vs baseline: 1.2076x; 1.0425x over previous
//
#include <hip/hip_runtime.h>
#include <cstdint>
#include <cstddef>
#include <cmath>

#define N_ROWS 30000
#define D_IN   784
#define NC     100
#define NCP    128
#define NSEG   12
#define SEG    30000
#define SORT_BLOCKS 118   // ceil(30000/256)
#define KP     800        // K padded to multiple of 32
#define MAXBLK 435        // ceil(27826/64) row-tiles
#define SL     16         // row-slices for k_dotQ

typedef short bf16x8 __attribute__((ext_vector_type(8)));
typedef float f32x4  __attribute__((ext_vector_type(4)));

struct Hdr {
  uint32_t kperm[12][2];
  uint32_t kw[12][2];
  uint32_t kb[12][2];
  uint32_t sub[12][2][2];
  int best; int pad0;
  float bsel;
  float r2arr[12];       // column norms of unnormalized Q columns
  float r1s[12 * SL];    // Q^T hc raw partials, SL slices per j
  float r1bs[12 * SL];   // reorth raw partials
  float R[144];      // 12x12 row-major
  float QT[120];     // 12x10
  float beta[120];   // 12x10
  float den[100];
  float num[1000];   // [c][j]
};

__device__ __forceinline__ void tf2x32(uint32_t k0, uint32_t k1,
                                       uint32_t x0, uint32_t x1,
                                       uint32_t& o0, uint32_t& o1) {
  const uint32_t kx = k0 ^ k1 ^ 0x1BD11BDAu;
  x0 += k0; x1 += k1;
  x0 += x1; x1 = (x1<<13)|(x1>>19); x1 ^= x0;
  x0 += x1; x1 = (x1<<15)|(x1>>17); x1 ^= x0;
  x0 += x1; x1 = (x1<<26)|(x1>>6);  x1 ^= x0;
  x0 += x1; x1 = (x1<<6) |(x1>>26); x1 ^= x0;
  x0 += k1; x1 += kx + 1u;
  x0 += x1; x1 = (x1<<17)|(x1>>15); x1 ^= x0;
  x0 += x1; x1 = (x1<<29)|(x1>>3);  x1 ^= x0;
  x0 += x1; x1 = (x1<<16)|(x1>>16); x1 ^= x0;
  x0 += x1; x1 = (x1<<24)|(x1>>8);  x1 ^= x0;
  x0 += kx; x1 += k0 + 2u;
  x0 += x1; x1 = (x1<<13)|(x1>>19); x1 ^= x0;
  x0 += x1; x1 = (x1<<15)|(x1>>17); x1 ^= x0;
  x0 += x1; x1 = (x1<<26)|(x1>>6);  x1 ^= x0;
  x0 += x1; x1 = (x1<<6) |(x1>>26); x1 ^= x0;
  x0 += k0; x1 += k1 + 3u;
  x0 += x1; x1 = (x1<<17)|(x1>>15); x1 ^= x0;
  x0 += x1; x1 = (x1<<29)|(x1>>3);  x1 ^= x0;
  x0 += x1; x1 = (x1<<16)|(x1>>16); x1 ^= x0;
  x0 += x1; x1 = (x1<<24)|(x1>>8);  x1 ^= x0;
  x0 += k1; x1 += kx + 4u;
  x0 += x1; x1 = (x1<<13)|(x1>>19); x1 ^= x0;
  x0 += x1; x1 = (x1<<15)|(x1>>17); x1 ^= x0;
  x0 += x1; x1 = (x1<<26)|(x1>>6);  x1 ^= x0;
  x0 += x1; x1 = (x1<<6) |(x1>>26); x1 ^= x0;
  x0 += kx; x1 += k0 + 5u;
  o0 = x0; o1 = x1;
}

__device__ __forceinline__ float u01(uint32_t bits) {
  return __uint_as_float((bits >> 9) | 0x3f800000u) - 1.0f;
}

__device__ __forceinline__ uint32_t rbits32(uint32_t k0, uint32_t k1, uint32_t idx) {
  uint32_t o0, o1;
  tf2x32(k0, k1, 0u, idx, o0, o1);
  return o0 ^ o1;
}

__device__ __forceinline__ ushort f2bf_rne(float f) {
  uint32_t u = __float_as_uint(f);
  return (ushort)((u + 0x7fffu + ((u >> 16) & 1u)) >> 16);
}
__device__ __forceinline__ float bf2f(ushort h) {
  return __uint_as_float(((uint32_t)h) << 16);
}

// ---------------- RNG key chain (jax_threefry_partitionable=True) ----------------
__global__ void k_rng_chain(Hdr* h) {
  if (threadIdx.x != 0 || blockIdx.x != 0) return;
  uint32_t c0 = 0u, c1 = 42u;
  for (int k = 0; k < 12; k++) {
    uint32_t t0, t1;
    tf2x32(c0, c1, 0u, 1u, t0, t1); h->kperm[k][0] = t0; h->kperm[k][1] = t1;
    tf2x32(c0, c1, 0u, 2u, t0, t1); h->kw[k][0]   = t0; h->kw[k][1]   = t1;
    tf2x32(c0, c1, 0u, 3u, t0, t1); h->kb[k][0]   = t0; h->kb[k][1]   = t1;
    uint32_t p0 = h->kperm[k][0], p1 = h->kperm[k][1];
    for (int r = 0; r < 2; r++) {
      uint32_t s0, s1, n0, n1;
      tf2x32(p0, p1, 0u, 1u, s0, s1);
      tf2x32(p0, p1, 0u, 0u, n0, n1);
      h->sub[k][r][0] = s0; h->sub[k][r][1] = s1;
      p0 = n0; p1 = n1;
    }
    tf2x32(c0, c1, 0u, 0u, t0, t1); c0 = t0; c1 = t1;
  }
}

// ---------------- X pre-split to bf16 hi/lo, KP-padded ----------------
__global__ __launch_bounds__(256) void k_splitX(const float* __restrict__ X,
    short* __restrict__ Xhi, short* __restrict__ Xlo) {
  int t = blockIdx.x * 256 + threadIdx.x;       // one thread per 8-elem group
  if (t >= N_ROWS * (KP / 8)) return;
  int i = t / (KP / 8), g = t % (KP / 8);
  int kb = g * 8;
  float v[8];
  if (kb + 8 <= D_IN) {
    const float* xr = X + (size_t)i * D_IN + kb;
    float4 p0 = *(const float4*)xr;
    float4 p1 = *(const float4*)(xr + 4);
    v[0]=p0.x; v[1]=p0.y; v[2]=p0.z; v[3]=p0.w;
    v[4]=p1.x; v[5]=p1.y; v[6]=p1.z; v[7]=p1.w;
  } else {
    #pragma unroll
    for (int q = 0; q < 8; q++) v[q] = 0.f;
  }
  uint32_t ph[4], pl[4];
  #pragma unroll
  for (int q = 0; q < 4; q++) {
    ushort h0 = f2bf_rne(v[2*q]),   h1 = f2bf_rne(v[2*q+1]);
    ushort l0 = f2bf_rne(v[2*q]   - bf2f(h0));
    ushort l1 = f2bf_rne(v[2*q+1] - bf2f(h1));
    ph[q] = (uint32_t)h0 | ((uint32_t)h1 << 16);
    pl[q] = (uint32_t)l0 | ((uint32_t)l1 << 16);
  }
  size_t o = (size_t)i * KP + kb;
  *(uint4*)(Xhi + o) = make_uint4(ph[0], ph[1], ph[2], ph[3]);
  *(uint4*)(Xlo + o) = make_uint4(pl[0], pl[1], pl[2], pl[3]);
}

// ---------------- radix sort (separate hist/scan/scatter) ----------------
__global__ __launch_bounds__(256) void k_keys_hist(const Hdr* __restrict__ h,
    uint32_t* __restrict__ keys, int* __restrict__ vals,
    uint32_t* __restrict__ hs, int round) {
  __shared__ uint32_t hloc[256];
  int s = blockIdx.x / SORT_BLOCKS, b = blockIdx.x % SORT_BLOCKS;
  int tid = threadIdx.x;
  hloc[tid] = 0;
  __syncthreads();
  int i = b * 256 + tid;
  if (i < SEG) {
    uint32_t key = rbits32(h->sub[s][round][0], h->sub[s][round][1], (uint32_t)i);
    keys[s * SEG + i] = key;
    if (round == 0) vals[s * SEG + i] = i;
    atomicAdd(&hloc[key & 255u], 1u);
  }
  __syncthreads();
  hs[(size_t)(s * SORT_BLOCKS + b) * 256 + tid] = hloc[tid];
}

__global__ __launch_bounds__(256) void k_hist(const uint32_t* __restrict__ keys,
    uint32_t* __restrict__ hs, int shift) {
  __shared__ uint32_t hloc[256];
  int s = blockIdx.x / SORT_BLOCKS, b = blockIdx.x % SORT_BLOCKS;
  hloc[threadIdx.x] = 0;
  __syncthreads();
  int i = b * 256 + threadIdx.x;
  if (i < SEG) {
    uint32_t d = (keys[s * SEG + i] >> shift) & 255u;
    atomicAdd(&hloc[d], 1u);
  }
  __syncthreads();
  hs[(size_t)(s * SORT_BLOCKS + b) * 256 + threadIdx.x] = hloc[threadIdx.x];
}

// chunked pipelined scan; per-(s,block) local offsets + per-(s,digit) base
__global__ __launch_bounds__(256) void k_scan(uint32_t* hs, uint32_t* baseA) {
  __shared__ uint32_t tot[256];
  __shared__ uint32_t base[256];
  int s = blockIdx.x, d = threadIdx.x;
  uint32_t run = 0;
  uint32_t buf[30];
  for (int c0 = 0; c0 < SORT_BLOCKS; c0 += 30) {
    int n = SORT_BLOCKS - c0; if (n > 30) n = 30;
    #pragma unroll
    for (int j = 0; j < 30; j++)
      if (j < n) buf[j] = hs[(size_t)(s * SORT_BLOCKS + c0 + j) * 256 + d];
    #pragma unroll
    for (int j = 0; j < 30; j++)
      if (j < n) {
        uint32_t c = buf[j];
        hs[(size_t)(s * SORT_BLOCKS + c0 + j) * 256 + d] = run;
        run += c;
      }
  }
  tot[d] = run;
  __syncthreads();
  if (d == 0) {
    uint32_t acc = 0;
    for (int q = 0; q < 256; q++) { base[q] = acc; acc += tot[q]; }
  }
  __syncthreads();
  baseA[s * 256 + d] = base[d];
}

__global__ __launch_bounds__(256) void k_scatter(const uint32_t* __restrict__ ik,
    const int* __restrict__ iv, uint32_t* __restrict__ ok, int* __restrict__ ov,
    const uint32_t* __restrict__ hs, const uint32_t* __restrict__ baseA, int shift) {
  __shared__ uint16_t wh[4][256];
  int s = blockIdx.x / SORT_BLOCKS, b = blockIdx.x % SORT_BLOCKS;
  int tid = threadIdx.x;
  for (int q = tid; q < 1024; q += 256) ((uint16_t*)wh)[q] = 0;
  __syncthreads();
  int i = b * 256 + tid;
  bool valid = (i < SEG);
  uint32_t key = 0, dg = 0; int val = 0;
  if (valid) {
    key = ik[s * SEG + i];
    val = iv[s * SEG + i];
    dg = (key >> shift) & 255u;
  }
  unsigned long long vm = __ballot(valid ? 1 : 0);
  unsigned long long m = ~0ULL;
  for (int bit = 0; bit < 8; bit++) {
    unsigned long long bm = __ballot((int)((dg >> bit) & 1u));
    m &= ((dg >> bit) & 1u) ? bm : ~bm;
  }
  m &= vm;
  int wv = tid >> 6, lane = tid & 63;
  int rw = __popcll(m & ((1ULL << lane) - 1ULL));
  if (valid && rw == 0) wh[wv][dg] = (uint16_t)__popcll(m);
  __syncthreads();
  if (valid) {
    int rank = rw;
    for (int q = 0; q < wv; q++) rank += wh[q][dg];
    uint32_t pos = hs[(size_t)(s * SORT_BLOCKS + b) * 256 + dg] + baseA[s * 256 + dg] + rank;
    ok[s * SEG + pos] = key;
    ov[s * SEG + pos] = val;
  }
}

// ---------------- candidate weight generation (W + b fused) ----------------
__global__ __launch_bounds__(256) void k_gen(const Hdr* __restrict__ h,
    float* __restrict__ Wr, short* __restrict__ Wthi, short* __restrict__ Wtlo,
    float* __restrict__ br) {
  int t = blockIdx.x * 256 + threadIdx.x;
  if (t >= NSEG * NCP * KP) return;
  if (t < NSEG * NC) {
    int k = t / NC, c = t % NC;
    float u = u01(rbits32(h->kb[k][0], h->kb[k][1], (uint32_t)c));
    float lam = (c < 50) ? 1.f : 10.f;
    br[t] = lam * (2.f * u - 1.f);
  }
  int seg = t / (NCP * KP);
  int r = t % (NCP * KP);
  int c = r / KP, d = r % KP;
  float val = 0.f;
  if (c < NC && d < D_IN) {
    int n = d * NC + c;  // row-major linear index of (784,100)
    float u = u01(rbits32(h->kw[seg][0], h->kw[seg][1], (uint32_t)n));
    float lam = (c < 50) ? 1.f : 10.f;
    val = lam * (2.f * u - 1.f);
  }
  ushort hi = f2bf_rne(val);
  ushort lo = f2bf_rne(val - bf2f(hi));
  Wthi[t] = (short)hi;
  Wtlo[t] = (short)lo;
  if (d < D_IN) Wr[(size_t)seg * D_IN * NCP + (size_t)d * NCP + c] = val;
}

// ---- MFMA split-bf16 candidate GEMM; LDS-staged; 64 rows x 64 cols (col-split) ----
// grid = 2 * row-tiles; bid = rb*2 + ch; block covers cols ch*64..ch*64+63.
// Per-(row,col) MFMA chain identical to the 128-col version (bit-exact).
__global__ __launch_bounds__(256) void k_batch_mfma(const short* __restrict__ Xhi,
    const short* __restrict__ Xlo,
    const short* __restrict__ Wthi, const short* __restrict__ Wtlo,
    const float* __restrict__ br, const int* __restrict__ perm,
    const float* __restrict__ Y, const float* __restrict__ Hbuf,
    const Hdr* __restrict__ hd, float* __restrict__ P, int kk, int bs) {
  __shared__ short Ah[64][40], Al[64][40];    // 80B row stride
  __shared__ short Bh[64][40], Bl[64][40];
  __shared__ int idxs[64];
  __shared__ float ekS[64][10];
  __shared__ float hS[64][12];
  __shared__ float betaS[120];
  int tid = threadIdx.x;
  int rb = blockIdx.x >> 1, ch = blockIdx.x & 1;
  int row0 = rb * 64;
  if (tid < 64) {
    int rr = row0 + tid;
    idxs[tid] = perm[rr < bs ? rr : (bs - 1)];
  }
  if (kk > 0 && tid < kk * 10) betaS[tid] = hd->beta[tid];
  __syncthreads();
  if (kk > 0) {
    for (int q = tid; q < 64 * kk; q += 256) {
      int r = q / kk, m = q % kk;
      hS[r][m] = Hbuf[(size_t)idxs[r] * 12 + m];
    }
  }
  __syncthreads();
  for (int q = tid; q < 640; q += 256) {
    int r = q / 10, j = q % 10;
    float e = 0.f;
    if (row0 + r < bs) {
      e = Y[(size_t)idxs[r] * 10 + j];
      if (kk > 0) {
        float yv = 0.f;
        for (int m = 0; m < kk; m++) yv += hS[r][m] * betaS[m * 10 + j];
        e -= yv;
      }
    }
    ekS[r][j] = e;
  }
  int wave = tid >> 6, lane = tid & 63;
  int kg = lane >> 4, ln = lane & 15;

  f32x4 acc[4];
  #pragma unroll
  for (int m = 0; m < 4; m++) acc[m] = (f32x4){0.f, 0.f, 0.f, 0.f};

  // A staging: 256 threads = 64 rows x 4 chunks; each thread loads hi+lo uint4
  int arow = tid >> 2, aq = tid & 3;
  // B staging: 256 threads = 64 cols x 4 chunks; each thread loads hi+lo uint4
  int bcg = tid >> 2, bq = tid & 3;
  size_t bgoff = (size_t)(ch * 64 + bcg) * KP + bq * 8;

  for (int k0 = 0; k0 < KP; k0 += 32) {
    __syncthreads();
    {  // stage A (coalesced copy of pre-split Xhi/Xlo)
      size_t o = (size_t)idxs[arow] * KP + k0 + aq * 8;
      *(uint4*)&Ah[arow][aq * 8] = *(const uint4*)(Xhi + o);
      *(uint4*)&Al[arow][aq * 8] = *(const uint4*)(Xlo + o);
    }
    {  // stage B half
      *(uint4*)&Bh[bcg][bq * 8] = *(const uint4*)(Wthi + bgoff + k0);
      *(uint4*)&Bl[bcg][bq * 8] = *(const uint4*)(Wtlo + bgoff + k0);
    }
    __syncthreads();
    bf16x8 bhf = *(bf16x8*)&Bh[wave * 16 + ln][kg * 8];
    bf16x8 blf = *(bf16x8*)&Bl[wave * 16 + ln][kg * 8];
    #pragma unroll
    for (int m = 0; m < 4; m++) {
      bf16x8 ah = *(bf16x8*)&Ah[m * 16 + ln][kg * 8];
      bf16x8 al = *(bf16x8*)&Al[m * 16 + ln][kg * 8];
      acc[m] = __builtin_amdgcn_mfma_f32_16x16x32_bf16(ah, bhf, acc[m], 0, 0, 0);
      acc[m] = __builtin_amdgcn_mfma_f32_16x16x32_bf16(ah, blf, acc[m], 0, 0, 0);
      acc[m] = __builtin_amdgcn_mfma_f32_16x16x32_bf16(al, bhf, acc[m], 0, 0, 0);
    }
  }
  // ---- fused epilogue: sigmoid + den/num partials, plain stores to P[rb] ----
  // C/D layout: col=lane&15, row=(lane>>4)*4+reg. Lanes kg=0..3 share a column.
  {
    int col = ch * 64 + wave * 16 + ln;
    float bias = (col < NC) ? br[col] : 0.f;
    float den_t = 0.f;
    float num_t[10];
    #pragma unroll
    for (int q = 0; q < 10; q++) num_t[q] = 0.f;
    #pragma unroll
    for (int m = 0; m < 4; m++) {
      #pragma unroll
      for (int r = 0; r < 4; r++) {
        int rl = m * 16 + kg * 4 + r;
        if (row0 + rl < bs) {
          float hsig = 1.f / (1.f + expf(-(acc[m][r] + bias)));
          den_t += hsig * hsig;
          #pragma unroll
          for (int q = 0; q < 10; q++) num_t[q] += hsig * ekS[rl][q];
        }
      }
    }
    den_t += __shfl_xor(den_t, 16, 64);
    den_t += __shfl_xor(den_t, 32, 64);
    #pragma unroll
    for (int q = 0; q < 10; q++) {
      num_t[q] += __shfl_xor(num_t[q], 16, 64);
      num_t[q] += __shfl_xor(num_t[q], 32, 64);
    }
    if (kg == 0 && col < NC) {
      float* dst = P + (size_t)rb * 1100 + col * 11;
      dst[0] = den_t;
      #pragma unroll
      for (int q = 0; q < 10; q++) dst[1 + q] = num_t[q];
    }
  }
}

// ---- score reduce + select + wcol (merged via last-block ticket, 100 blocks) ----
__global__ __launch_bounds__(256) void k_score_select(const float* __restrict__ P,
    Hdr* h, const float* __restrict__ brk, const float* __restrict__ Wr,
    float* __restrict__ wcol, float* __restrict__ outW, float* __restrict__ outB,
    int* __restrict__ ticket, int k, int nblk) {
  int c = blockIdx.x;           // 0..99
  int tid = threadIdx.x;
  int q = tid % 11, g = tid / 11;   // 23 groups of 11
  float acc = 0.f;
  if (tid < 253) {
    for (int b = g; b < nblk; b += 23)
      acc += P[(size_t)b * 1100 + c * 11 + q];
  }
  __shared__ float red[23][11];
  if (tid < 253) red[g][q] = acc;
  __syncthreads();
  if (tid < 11) {
    float s = 0.f;
    #pragma unroll
    for (int g2 = 0; g2 < 23; g2++) s += red[g2][tid];
    if (tid == 0) h->den[c] = s;
    else h->num[c * 10 + tid - 1] = s;
  }
  __shared__ int sdone;
  __syncthreads();
  __threadfence();
  if (tid == 0) {
    int old = atomicAdd(ticket, 1);
    sdone = (old == NC - 1) ? 1 : 0;
  }
  __syncthreads();
  if (!sdone) return;
  __threadfence();
  __shared__ int sbest;
  if (tid < 12 * SL) { h->r1s[tid] = 0.f; h->r1bs[tid] = 0.f; }
  if (tid == 0) {
    float best = -1.f; int bi = 0;
    for (int cc = 0; cc < NC; cc++) {
      float s = 0.f;
      for (int j = 0; j < 10; j++) { float n = h->num[cc * 10 + j]; s += n * n; }
      float v = s / (h->den[cc] * 10.f);
      if (v > best) { best = v; bi = cc; }
    }
    h->best = bi;
    h->bsel = brk[bi];
    outB[k] = h->bsel;
    sbest = bi;
  }
  __syncthreads();
  int best = sbest;
  for (int d = tid; d < D_IN; d += 256) {
    float v = Wr[(size_t)d * NCP + best];
    wcol[d] = v;
    outW[d * 12 + k] = v;
  }
}

// ---- hc for all rows: one wave per row, float4 loads ----
__global__ __launch_bounds__(256) void k_hc(const float* __restrict__ X,
    const Hdr* __restrict__ h, const float* __restrict__ wcol,
    float* __restrict__ H, float* __restrict__ hc, int k) {
  int lane = threadIdx.x & 63;
  int row = blockIdx.x * 4 + (threadIdx.x >> 6);
  if (row >= N_ROWS) return;
  const float4* xp = (const float4*)(X + (size_t)row * D_IN);
  const float4* wp = (const float4*)wcol;
  float acc = 0.f;
  #pragma unroll
  for (int it = 0; it < 4; it++) {
    int p = lane + it * 64;
    if (p < 196) {
      float4 xv = xp[p], wv = wp[p];
      acc += xv.x * wv.x + xv.y * wv.y + xv.z * wv.z + xv.w * wv.w;
    }
  }
  #pragma unroll
  for (int o = 32; o > 0; o >>= 1) acc += __shfl_xor(acc, o, 64);
  if (lane == 0) {
    float hv = 1.f / (1.f + expf(-(acc + h->bsel)));
    H[(size_t)row * 12 + k] = hv;
    hc[row] = hv;
  }
}

// ---- T^T vec (unnormalized Q columns) with SL-way row-slice split ----
__global__ __launch_bounds__(256) void k_dotQ(const float* __restrict__ Tcm,
    const float* __restrict__ vec, float* __restrict__ dst) {
  int j = blockIdx.x / SL, sl = blockIdx.x % SL;
  const float* q = Tcm + (size_t)j * N_ROWS;
  int i0 = sl * (N_ROWS / SL);
  int i1 = i0 + (N_ROWS / SL);
  float a = 0.f;
  for (int i = i0 + threadIdx.x; i < i1; i += 256) a += q[i] * vec[i];
  __shared__ float red[256];
  red[threadIdx.x] = a;
  __syncthreads();
  for (int s = 128; s > 0; s >>= 1) {
    if (threadIdx.x < s) red[threadIdx.x] += red[threadIdx.x + s];
    __syncthreads();
  }
  if (threadIdx.x == 0) dst[j * SL + sl] = red[0];
}

// ---- t = basev - T cf (cf = raw/(r2_j^2)); writes T[:,k]; partials of t^2, t·Y_j;
//      dofin: last block assembles r2, QT row, R col, backsub (118 blocks) ----
__global__ __launch_bounds__(256) void k_sub_fin(Hdr* h, float* __restrict__ Tcm,
    const float* __restrict__ basev, const float* __restrict__ coefp,
    const float* __restrict__ Y, float* __restrict__ partials,
    float* __restrict__ out_beta, int* __restrict__ ticket, int k, int dofin) {
  __shared__ float cf[12];
  int tid = threadIdx.x;
  if (tid < 12) {
    float s = 0.f;
    #pragma unroll
    for (int s8 = 0; s8 < SL; s8++) s += coefp[tid * SL + s8];
    float r2j = (tid < k) ? h->r2arr[tid] : 1.f;
    cf[tid] = s / (r2j * r2j);
  }
  __syncthreads();
  int i = blockIdx.x * 256 + tid;
  float t = 0.f;
  float v[11];
  #pragma unroll
  for (int q = 0; q < 11; q++) v[q] = 0.f;
  if (i < N_ROWS) {
    t = basev[i];
    for (int j = 0; j < k; j++) t -= Tcm[(size_t)j * N_ROWS + i] * cf[j];
    Tcm[(size_t)k * N_ROWS + i] = t;
    if (dofin) {
      const float* yr = Y + (size_t)i * 10;
      #pragma unroll
      for (int q = 0; q < 10; q++) v[q] = t * yr[q];
      v[10] = t * t;
    }
  }
  if (!dofin) return;
  #pragma unroll
  for (int o = 1; o < 64; o <<= 1) {
    #pragma unroll
    for (int q = 0; q < 11; q++) v[q] += __shfl_xor(v[q], o, 64);
  }
  __shared__ float wred[4][11];
  int wave = tid >> 6, lane = tid & 63;
  if (lane == 0) {
    #pragma unroll
    for (int q = 0; q < 11; q++) wred[wave][q] = v[q];
  }
  __syncthreads();
  if (tid < 11) {
    float s = wred[0][tid] + wred[1][tid] + wred[2][tid] + wred[3][tid];
    partials[blockIdx.x * 12 + tid] = s;
  }
  // ---- last-block finalize ----
  __shared__ int sdone;
  __syncthreads();
  __threadfence();
  if (tid == 0) {
    int old = atomicAdd(ticket, 1);
    sdone = (old == SORT_BLOCKS - 1) ? 1 : 0;
  }
  __syncthreads();
  if (!sdone) return;
  __threadfence();
  __shared__ float red[23][11];
  int q = tid % 11, g = tid / 11;
  float acc2 = 0.f;
  if (tid < 253) {
    for (int b = g; b < SORT_BLOCKS; b += 23)
      acc2 += partials[b * 12 + q];
  }
  if (tid < 253) red[g][q] = acc2;
  __syncthreads();
  __shared__ float s[11];
  __shared__ float Rcol[12];
  __shared__ float r2s;
  if (tid < 11) {
    float ss = 0.f;
    #pragma unroll
    for (int g2 = 0; g2 < 23; g2++) ss += red[g2][tid];
    s[tid] = ss;
  }
  __syncthreads();
  if (tid == 0) {
    float r2 = sqrtf(s[10]);
    h->r2arr[k] = r2;
    h->R[k * 12 + k] = r2;
    r2s = r2;
    Rcol[k] = r2;
    for (int i2 = 0; i2 < k; i2++) {
      float rs = 0.f;
      #pragma unroll
      for (int s8 = 0; s8 < SL; s8++) rs += h->r1s[i2 * SL + s8] + h->r1bs[i2 * SL + s8];
      float Rik = rs / h->r2arr[i2];
      h->R[i2 * 12 + k] = Rik;
      Rcol[i2] = Rik;
    }
  }
  __syncthreads();
  if (tid < 10) {
    float qtk = s[tid] / r2s;
    h->QT[k * 10 + tid] = qtk;
    float bloc[12];
    for (int i2 = k; i2 >= 0; i2--) {
      float t2 = (i2 == k) ? qtk : h->QT[i2 * 10 + tid];
      for (int m = i2 + 1; m <= k; m++) {
        float Rim = (m == k) ? Rcol[i2] : h->R[i2 * 12 + m];
        t2 -= Rim * bloc[m];
      }
      t2 /= ((i2 == k) ? r2s : h->R[i2 * 12 + i2]);
      bloc[i2] = t2;
      h->beta[i2 * 10 + tid] = t2;
      out_beta[i2 * 10 + tid] = t2;
    }
  }
}

static inline int cdiv(int a, int b) { return (a + b - 1) / b; }

extern "C" void kernel_launch(void* const* d_in, const int* in_sizes, int n_in,
                              void* d_out, int out_size, void* d_ws, size_t ws_size,
                              hipStream_t stream) {
  const float* X = (const float*)d_in[0];
  const float* Y = (const float*)d_in[1];
  float* out = (float*)d_out;
  float* outW = out;             // 784*12
  float* outB = out + 9408;      // 12
  float* outBeta = out + 9420;   // 12*10

  char* base = (char*)d_ws;
  Hdr* hdr = (Hdr*)base;
  float* r1p  = (float*)(base + offsetof(Hdr, r1s));
  float* r1bp = (float*)(base + offsetof(Hdr, r1bs));

  size_t off = 16384;
  auto nxt = [&](size_t bytes) -> void* {
    void* p = base + off;
    off += (bytes + 255) & ~(size_t)255;
    return p;
  };
  int* tickets = (int*)nxt(1024);   // [0..11] score, [32..43] subfin
  uint32_t* keysA = (uint32_t*)nxt((size_t)NSEG * SEG * 4);
  uint32_t* keysB = (uint32_t*)nxt((size_t)NSEG * SEG * 4);
  int* valsA = (int*)nxt((size_t)NSEG * SEG * 4);
  int* valsB = (int*)nxt((size_t)NSEG * SEG * 4);
  uint32_t* hs = (uint32_t*)nxt((size_t)NSEG * SORT_BLOCKS * 256 * 4);
  uint32_t* baseA = (uint32_t*)nxt((size_t)NSEG * 256 * 4);
  float* WrAll = (float*)nxt((size_t)NSEG * D_IN * NCP * 4);
  short* WthiAll = (short*)nxt((size_t)NSEG * NCP * KP * 2);
  short* WtloAll = (short*)nxt((size_t)NSEG * NCP * KP * 2);
  float* brAll = (float*)nxt((size_t)NSEG * NC * 4);
  float* wcol = (float*)nxt((size_t)D_IN * 4);
  float* Pbuf = (float*)nxt((size_t)MAXBLK * 1100 * 4);
  float* Tcm = (float*)nxt((size_t)12 * N_ROWS * 4);
  float* Hbuf = (float*)nxt((size_t)N_ROWS * 12 * 4);
  float* hcbuf = (float*)nxt((size_t)N_ROWS * 4);
  float* partials = (float*)nxt(128 * 12 * 4);
  short* Xhi = (short*)nxt((size_t)N_ROWS * KP * 2);
  short* Xlo = (short*)nxt((size_t)N_ROWS * KP * 2);

  hipMemsetAsync(tickets, 0, 1024, stream);

  // 1. RNG key chain + X pre-split
  k_rng_chain<<<1, 64, 0, stream>>>(hdr);
  k_splitX<<<cdiv(N_ROWS * (KP / 8), 256), 256, 0, stream>>>(X, Xhi, Xlo);

  // 2. permutations: 2 rounds x 4 radix passes (keygen fused into pass-0 hist only)
  const int sortgrid = NSEG * SORT_BLOCKS;
  for (int round = 0; round < 2; round++) {
    k_keys_hist<<<sortgrid, 256, 0, stream>>>(hdr, keysA, valsA, hs, round);
    k_scan<<<NSEG, 256, 0, stream>>>(hs, baseA);
    k_scatter<<<sortgrid, 256, 0, stream>>>(keysA, valsA, keysB, valsB, hs, baseA, 0);
    for (int pass = 1; pass < 4; pass++) {
      uint32_t* ik = (pass & 1) ? keysB : keysA;
      uint32_t* ok = (pass & 1) ? keysA : keysB;
      int* iv = (pass & 1) ? valsB : valsA;
      int* ov = (pass & 1) ? valsA : valsB;
      k_hist<<<sortgrid, 256, 0, stream>>>(ik, hs, 8 * pass);
      k_scan<<<NSEG, 256, 0, stream>>>(hs, baseA);
      k_scatter<<<sortgrid, 256, 0, stream>>>(ik, iv, ok, ov, hs, baseA, 8 * pass);
    }
  }

  // 3. candidate weights (fp32 + transposed bf16 hi/lo + biases, one kernel)
  k_gen<<<cdiv(NSEG * NCP * KP, 256), 256, 0, stream>>>(hdr, WrAll, WthiAll, WtloAll, brAll);

  // 4. sequential training loop
  for (int k = 0; k < 12; k++) {
    int bs = 4000 + 2166 * k;
    int nblk_row = cdiv(bs, 64);
    const int* perm = valsA + (size_t)k * SEG;
    const short* Wthi = WthiAll + (size_t)k * NCP * KP;
    const short* Wtlo = WtloAll + (size_t)k * NCP * KP;
    const float* brk = brAll + (size_t)k * NC;

    k_batch_mfma<<<nblk_row * 2, 256, 0, stream>>>(Xhi, Xlo, Wthi, Wtlo, brk, perm, Y, Hbuf, hdr, Pbuf, k, bs);
    k_score_select<<<NC, 256, 0, stream>>>(Pbuf, hdr, brk,
        WrAll + (size_t)k * D_IN * NCP, wcol, outW, outB, &tickets[k], k, nblk_row);
    k_hc<<<7500, 256, 0, stream>>>(X, hdr, wcol, Hbuf, hcbuf, k);
    if (k > 0) k_dotQ<<<k * SL, 256, 0, stream>>>(Tcm, hcbuf, r1p);
    if (k == 1 || k == 2) {
      // reorthogonalize (emulates inv/Householder branches): pass1 no-fin
      k_sub_fin<<<SORT_BLOCKS, 256, 0, stream>>>(hdr, Tcm, hcbuf, r1p, Y, partials,
          outBeta, &tickets[32 + k], k, 0);
      k_dotQ<<<k * SL, 256, 0, stream>>>(Tcm, Tcm + (size_t)k * N_ROWS, r1bp);
      k_sub_fin<<<SORT_BLOCKS, 256, 0, stream>>>(hdr, Tcm, Tcm + (size_t)k * N_ROWS, r1bp,
          Y, partials, outBeta, &tickets[32 + k], k, 1);
    } else {
      k_sub_fin<<<SORT_BLOCKS, 256, 0, stream>>>(hdr, Tcm, hcbuf, r1p, Y, partials,
          outBeta, &tickets[32 + k], k, 1);
    }
  }
}

// Round 14
// 1547.063 us; speedup vs baseline: 1.2450x; 1.0310x over previous
//
#include <hip/hip_runtime.h>
#include <cstdint>
#include <cstddef>
#include <cmath>

#define N_ROWS 30000
#define D_IN   784
#define NC     100
#define NCP    128
#define NSEG   12
#define SEG    30000
#define SORT_BLOCKS 118   // ceil(30000/256)
#define KP     832        // K padded to multiple of 64 (zero pad: bit-exact)
#define MAXBLK 435        // ceil(27826/64) row-tiles
#define SL     16         // row-slices for k_dotQ

typedef short bf16x8 __attribute__((ext_vector_type(8)));
typedef float f32x4  __attribute__((ext_vector_type(4)));

struct Hdr {
  uint32_t kperm[12][2];
  uint32_t kw[12][2];
  uint32_t kb[12][2];
  uint32_t sub[12][2][2];
  int best; int pad0;
  float bsel;
  float r2arr[12];       // column norms of unnormalized Q columns
  float r1s[12 * SL];    // Q^T hc raw partials, SL slices per j
  float r1bs[12 * SL];   // reorth raw partials
  float R[144];      // 12x12 row-major
  float QT[120];     // 12x10
  float beta[120];   // 12x10
  float den[100];
  float num[1000];   // [c][j]
};

__device__ __forceinline__ void tf2x32(uint32_t k0, uint32_t k1,
                                       uint32_t x0, uint32_t x1,
                                       uint32_t& o0, uint32_t& o1) {
  const uint32_t kx = k0 ^ k1 ^ 0x1BD11BDAu;
  x0 += k0; x1 += k1;
  x0 += x1; x1 = (x1<<13)|(x1>>19); x1 ^= x0;
  x0 += x1; x1 = (x1<<15)|(x1>>17); x1 ^= x0;
  x0 += x1; x1 = (x1<<26)|(x1>>6);  x1 ^= x0;
  x0 += x1; x1 = (x1<<6) |(x1>>26); x1 ^= x0;
  x0 += k1; x1 += kx + 1u;
  x0 += x1; x1 = (x1<<17)|(x1>>15); x1 ^= x0;
  x0 += x1; x1 = (x1<<29)|(x1>>3);  x1 ^= x0;
  x0 += x1; x1 = (x1<<16)|(x1>>16); x1 ^= x0;
  x0 += x1; x1 = (x1<<24)|(x1>>8);  x1 ^= x0;
  x0 += kx; x1 += k0 + 2u;
  x0 += x1; x1 = (x1<<13)|(x1>>19); x1 ^= x0;
  x0 += x1; x1 = (x1<<15)|(x1>>17); x1 ^= x0;
  x0 += x1; x1 = (x1<<26)|(x1>>6);  x1 ^= x0;
  x0 += x1; x1 = (x1<<6) |(x1>>26); x1 ^= x0;
  x0 += k0; x1 += k1 + 3u;
  x0 += x1; x1 = (x1<<17)|(x1>>15); x1 ^= x0;
  x0 += x1; x1 = (x1<<29)|(x1>>3);  x1 ^= x0;
  x0 += x1; x1 = (x1<<16)|(x1>>16); x1 ^= x0;
  x0 += x1; x1 = (x1<<24)|(x1>>8);  x1 ^= x0;
  x0 += k1; x1 += kx + 4u;
  x0 += x1; x1 = (x1<<13)|(x1>>19); x1 ^= x0;
  x0 += x1; x1 = (x1<<15)|(x1>>17); x1 ^= x0;
  x0 += x1; x1 = (x1<<26)|(x1>>6);  x1 ^= x0;
  x0 += x1; x1 = (x1<<6) |(x1>>26); x1 ^= x0;
  x0 += kx; x1 += k0 + 5u;
  o0 = x0; o1 = x1;
}

__device__ __forceinline__ float u01(uint32_t bits) {
  return __uint_as_float((bits >> 9) | 0x3f800000u) - 1.0f;
}

__device__ __forceinline__ uint32_t rbits32(uint32_t k0, uint32_t k1, uint32_t idx) {
  uint32_t o0, o1;
  tf2x32(k0, k1, 0u, idx, o0, o1);
  return o0 ^ o1;
}

__device__ __forceinline__ ushort f2bf_rne(float f) {
  uint32_t u = __float_as_uint(f);
  return (ushort)((u + 0x7fffu + ((u >> 16) & 1u)) >> 16);
}
__device__ __forceinline__ float bf2f(ushort h) {
  return __uint_as_float(((uint32_t)h) << 16);
}

// ---------------- RNG key chain (jax_threefry_partitionable=True) ----------------
__global__ void k_rng_chain(Hdr* h) {
  if (threadIdx.x != 0 || blockIdx.x != 0) return;
  uint32_t c0 = 0u, c1 = 42u;
  for (int k = 0; k < 12; k++) {
    uint32_t t0, t1;
    tf2x32(c0, c1, 0u, 1u, t0, t1); h->kperm[k][0] = t0; h->kperm[k][1] = t1;
    tf2x32(c0, c1, 0u, 2u, t0, t1); h->kw[k][0]   = t0; h->kw[k][1]   = t1;
    tf2x32(c0, c1, 0u, 3u, t0, t1); h->kb[k][0]   = t0; h->kb[k][1]   = t1;
    uint32_t p0 = h->kperm[k][0], p1 = h->kperm[k][1];
    for (int r = 0; r < 2; r++) {
      uint32_t s0, s1, n0, n1;
      tf2x32(p0, p1, 0u, 1u, s0, s1);
      tf2x32(p0, p1, 0u, 0u, n0, n1);
      h->sub[k][r][0] = s0; h->sub[k][r][1] = s1;
      p0 = n0; p1 = n1;
    }
    tf2x32(c0, c1, 0u, 0u, t0, t1); c0 = t0; c1 = t1;
  }
}

// ---------------- X pre-split to bf16 hi/lo, KP-padded ----------------
__global__ __launch_bounds__(256) void k_splitX(const float* __restrict__ X,
    short* __restrict__ Xhi, short* __restrict__ Xlo) {
  int t = blockIdx.x * 256 + threadIdx.x;       // one thread per 8-elem group
  if (t >= N_ROWS * (KP / 8)) return;
  int i = t / (KP / 8), g = t % (KP / 8);
  int kb = g * 8;
  float v[8];
  if (kb + 8 <= D_IN) {
    const float* xr = X + (size_t)i * D_IN + kb;
    float4 p0 = *(const float4*)xr;
    float4 p1 = *(const float4*)(xr + 4);
    v[0]=p0.x; v[1]=p0.y; v[2]=p0.z; v[3]=p0.w;
    v[4]=p1.x; v[5]=p1.y; v[6]=p1.z; v[7]=p1.w;
  } else {
    #pragma unroll
    for (int q = 0; q < 8; q++) v[q] = 0.f;
  }
  uint32_t ph[4], pl[4];
  #pragma unroll
  for (int q = 0; q < 4; q++) {
    ushort h0 = f2bf_rne(v[2*q]),   h1 = f2bf_rne(v[2*q+1]);
    ushort l0 = f2bf_rne(v[2*q]   - bf2f(h0));
    ushort l1 = f2bf_rne(v[2*q+1] - bf2f(h1));
    ph[q] = (uint32_t)h0 | ((uint32_t)h1 << 16);
    pl[q] = (uint32_t)l0 | ((uint32_t)l1 << 16);
  }
  size_t o = (size_t)i * KP + kb;
  *(uint4*)(Xhi + o) = make_uint4(ph[0], ph[1], ph[2], ph[3]);
  *(uint4*)(Xlo + o) = make_uint4(pl[0], pl[1], pl[2], pl[3]);
}

// ---------------- radix sort (separate hist/scan/scatter) ----------------
__global__ __launch_bounds__(256) void k_keys_hist(const Hdr* __restrict__ h,
    uint32_t* __restrict__ keys, int* __restrict__ vals,
    uint32_t* __restrict__ hs, int round) {
  __shared__ uint32_t hloc[256];
  int s = blockIdx.x / SORT_BLOCKS, b = blockIdx.x % SORT_BLOCKS;
  int tid = threadIdx.x;
  hloc[tid] = 0;
  __syncthreads();
  int i = b * 256 + tid;
  if (i < SEG) {
    uint32_t key = rbits32(h->sub[s][round][0], h->sub[s][round][1], (uint32_t)i);
    keys[s * SEG + i] = key;
    if (round == 0) vals[s * SEG + i] = i;
    atomicAdd(&hloc[key & 255u], 1u);
  }
  __syncthreads();
  hs[(size_t)(s * SORT_BLOCKS + b) * 256 + tid] = hloc[tid];
}

__global__ __launch_bounds__(256) void k_hist(const uint32_t* __restrict__ keys,
    uint32_t* __restrict__ hs, int shift) {
  __shared__ uint32_t hloc[256];
  int s = blockIdx.x / SORT_BLOCKS, b = blockIdx.x % SORT_BLOCKS;
  hloc[threadIdx.x] = 0;
  __syncthreads();
  int i = b * 256 + threadIdx.x;
  if (i < SEG) {
    uint32_t d = (keys[s * SEG + i] >> shift) & 255u;
    atomicAdd(&hloc[d], 1u);
  }
  __syncthreads();
  hs[(size_t)(s * SORT_BLOCKS + b) * 256 + threadIdx.x] = hloc[threadIdx.x];
}

// chunked pipelined scan; per-(s,block) local offsets + per-(s,digit) base
__global__ __launch_bounds__(256) void k_scan(uint32_t* hs, uint32_t* baseA) {
  __shared__ uint32_t tot[256];
  __shared__ uint32_t base[256];
  int s = blockIdx.x, d = threadIdx.x;
  uint32_t run = 0;
  uint32_t buf[30];
  for (int c0 = 0; c0 < SORT_BLOCKS; c0 += 30) {
    int n = SORT_BLOCKS - c0; if (n > 30) n = 30;
    #pragma unroll
    for (int j = 0; j < 30; j++)
      if (j < n) buf[j] = hs[(size_t)(s * SORT_BLOCKS + c0 + j) * 256 + d];
    #pragma unroll
    for (int j = 0; j < 30; j++)
      if (j < n) {
        uint32_t c = buf[j];
        hs[(size_t)(s * SORT_BLOCKS + c0 + j) * 256 + d] = run;
        run += c;
      }
  }
  tot[d] = run;
  __syncthreads();
  if (d == 0) {
    uint32_t acc = 0;
    for (int q = 0; q < 256; q++) { base[q] = acc; acc += tot[q]; }
  }
  __syncthreads();
  baseA[s * 256 + d] = base[d];
}

__global__ __launch_bounds__(256) void k_scatter(const uint32_t* __restrict__ ik,
    const int* __restrict__ iv, uint32_t* __restrict__ ok, int* __restrict__ ov,
    const uint32_t* __restrict__ hs, const uint32_t* __restrict__ baseA, int shift) {
  __shared__ uint16_t wh[4][256];
  int s = blockIdx.x / SORT_BLOCKS, b = blockIdx.x % SORT_BLOCKS;
  int tid = threadIdx.x;
  for (int q = tid; q < 1024; q += 256) ((uint16_t*)wh)[q] = 0;
  __syncthreads();
  int i = b * 256 + tid;
  bool valid = (i < SEG);
  uint32_t key = 0, dg = 0; int val = 0;
  if (valid) {
    key = ik[s * SEG + i];
    val = iv[s * SEG + i];
    dg = (key >> shift) & 255u;
  }
  unsigned long long vm = __ballot(valid ? 1 : 0);
  unsigned long long m = ~0ULL;
  for (int bit = 0; bit < 8; bit++) {
    unsigned long long bm = __ballot((int)((dg >> bit) & 1u));
    m &= ((dg >> bit) & 1u) ? bm : ~bm;
  }
  m &= vm;
  int wv = tid >> 6, lane = tid & 63;
  int rw = __popcll(m & ((1ULL << lane) - 1ULL));
  if (valid && rw == 0) wh[wv][dg] = (uint16_t)__popcll(m);
  __syncthreads();
  if (valid) {
    int rank = rw;
    for (int q = 0; q < wv; q++) rank += wh[q][dg];
    uint32_t pos = hs[(size_t)(s * SORT_BLOCKS + b) * 256 + dg] + baseA[s * 256 + dg] + rank;
    ok[s * SEG + pos] = key;
    ov[s * SEG + pos] = val;
  }
}

// ---------------- candidate weight generation (W + b fused) ----------------
__global__ __launch_bounds__(256) void k_gen(const Hdr* __restrict__ h,
    float* __restrict__ Wr, short* __restrict__ Wthi, short* __restrict__ Wtlo,
    float* __restrict__ br) {
  int t = blockIdx.x * 256 + threadIdx.x;
  if (t >= NSEG * NCP * KP) return;
  if (t < NSEG * NC) {
    int k = t / NC, c = t % NC;
    float u = u01(rbits32(h->kb[k][0], h->kb[k][1], (uint32_t)c));
    float lam = (c < 50) ? 1.f : 10.f;
    br[t] = lam * (2.f * u - 1.f);
  }
  int seg = t / (NCP * KP);
  int r = t % (NCP * KP);
  int c = r / KP, d = r % KP;
  float val = 0.f;
  if (c < NC && d < D_IN) {
    int n = d * NC + c;  // row-major linear index of (784,100)
    float u = u01(rbits32(h->kw[seg][0], h->kw[seg][1], (uint32_t)n));
    float lam = (c < 50) ? 1.f : 10.f;
    val = lam * (2.f * u - 1.f);
  }
  ushort hi = f2bf_rne(val);
  ushort lo = f2bf_rne(val - bf2f(hi));
  Wthi[t] = (short)hi;
  Wtlo[t] = (short)lo;
  if (d < D_IN) Wr[(size_t)seg * D_IN * NCP + (size_t)d * NCP + c] = val;
}

// ---- MFMA split-bf16 candidate GEMM; LDS-staged; 64 rows x 64 cols, BK=64 ----
// grid = 2 * row-tiles; bid = rb*2 + ch; block covers cols ch*64..ch*64+63.
// BK=64 halves barrier count vs BK=32; per-(row,col) MFMA chain order unchanged
// (ascending k, same 3-product pattern) -> bit-exact.
__global__ __launch_bounds__(256) void k_batch_mfma(const short* __restrict__ Xhi,
    const short* __restrict__ Xlo,
    const short* __restrict__ Wthi, const short* __restrict__ Wtlo,
    const float* __restrict__ br, const int* __restrict__ perm,
    const float* __restrict__ Y, const float* __restrict__ Hbuf,
    const Hdr* __restrict__ hd, float* __restrict__ P, int kk, int bs) {
  __shared__ short Ah[64][72], Al[64][72];    // 144B row stride
  __shared__ short Bh[64][72], Bl[64][72];
  __shared__ int idxs[64];
  __shared__ float ekS[64][10];
  __shared__ float hS[64][12];
  __shared__ float betaS[120];
  int tid = threadIdx.x;
  int rb = blockIdx.x >> 1, ch = blockIdx.x & 1;
  int row0 = rb * 64;
  if (tid < 64) {
    int rr = row0 + tid;
    idxs[tid] = perm[rr < bs ? rr : (bs - 1)];
  }
  if (kk > 0 && tid < kk * 10) betaS[tid] = hd->beta[tid];
  __syncthreads();
  if (kk > 0) {
    for (int q = tid; q < 64 * kk; q += 256) {
      int r = q / kk, m = q % kk;
      hS[r][m] = Hbuf[(size_t)idxs[r] * 12 + m];
    }
  }
  __syncthreads();
  for (int q = tid; q < 640; q += 256) {
    int r = q / 10, j = q % 10;
    float e = 0.f;
    if (row0 + r < bs) {
      e = Y[(size_t)idxs[r] * 10 + j];
      if (kk > 0) {
        float yv = 0.f;
        for (int m = 0; m < kk; m++) yv += hS[r][m] * betaS[m * 10 + j];
        e -= yv;
      }
    }
    ekS[r][j] = e;
  }
  int wave = tid >> 6, lane = tid & 63;
  int kg = lane >> 4, ln = lane & 15;

  f32x4 acc[4];
  #pragma unroll
  for (int m = 0; m < 4; m++) acc[m] = (f32x4){0.f, 0.f, 0.f, 0.f};

  // A staging: 256 threads = 64 rows x 4 slots; each slot loads chunks aq and aq+4
  int arow = tid >> 2, aq = tid & 3;
  // B staging: 64 cols x 4 slots, chunks bq and bq+4
  int bcg = tid >> 2, bq = tid & 3;
  size_t bgoff = (size_t)(ch * 64 + bcg) * KP;

  for (int k0 = 0; k0 < KP; k0 += 64) {
    __syncthreads();
    {  // stage A (coalesced copy of pre-split Xhi/Xlo), 64-wide K
      size_t o = (size_t)idxs[arow] * KP + k0;
      *(uint4*)&Ah[arow][aq * 8]      = *(const uint4*)(Xhi + o + aq * 8);
      *(uint4*)&Ah[arow][aq * 8 + 32] = *(const uint4*)(Xhi + o + aq * 8 + 32);
      *(uint4*)&Al[arow][aq * 8]      = *(const uint4*)(Xlo + o + aq * 8);
      *(uint4*)&Al[arow][aq * 8 + 32] = *(const uint4*)(Xlo + o + aq * 8 + 32);
    }
    {  // stage B half, 64-wide K
      size_t o = bgoff + k0;
      *(uint4*)&Bh[bcg][bq * 8]      = *(const uint4*)(Wthi + o + bq * 8);
      *(uint4*)&Bh[bcg][bq * 8 + 32] = *(const uint4*)(Wthi + o + bq * 8 + 32);
      *(uint4*)&Bl[bcg][bq * 8]      = *(const uint4*)(Wtlo + o + bq * 8);
      *(uint4*)&Bl[bcg][bq * 8 + 32] = *(const uint4*)(Wtlo + o + bq * 8 + 32);
    }
    __syncthreads();
    #pragma unroll
    for (int sub = 0; sub < 2; sub++) {
      int co = sub * 32 + kg * 8;
      bf16x8 bhf = *(bf16x8*)&Bh[wave * 16 + ln][co];
      bf16x8 blf = *(bf16x8*)&Bl[wave * 16 + ln][co];
      #pragma unroll
      for (int m = 0; m < 4; m++) {
        bf16x8 ah = *(bf16x8*)&Ah[m * 16 + ln][co];
        bf16x8 al = *(bf16x8*)&Al[m * 16 + ln][co];
        acc[m] = __builtin_amdgcn_mfma_f32_16x16x32_bf16(ah, bhf, acc[m], 0, 0, 0);
        acc[m] = __builtin_amdgcn_mfma_f32_16x16x32_bf16(ah, blf, acc[m], 0, 0, 0);
        acc[m] = __builtin_amdgcn_mfma_f32_16x16x32_bf16(al, bhf, acc[m], 0, 0, 0);
      }
    }
  }
  // ---- fused epilogue: sigmoid + den/num partials, plain stores to P[rb] ----
  // C/D layout: col=lane&15, row=(lane>>4)*4+reg. Lanes kg=0..3 share a column.
  {
    int col = ch * 64 + wave * 16 + ln;
    float bias = (col < NC) ? br[col] : 0.f;
    float den_t = 0.f;
    float num_t[10];
    #pragma unroll
    for (int q = 0; q < 10; q++) num_t[q] = 0.f;
    #pragma unroll
    for (int m = 0; m < 4; m++) {
      #pragma unroll
      for (int r = 0; r < 4; r++) {
        int rl = m * 16 + kg * 4 + r;
        if (row0 + rl < bs) {
          float hsig = 1.f / (1.f + expf(-(acc[m][r] + bias)));
          den_t += hsig * hsig;
          #pragma unroll
          for (int q = 0; q < 10; q++) num_t[q] += hsig * ekS[rl][q];
        }
      }
    }
    den_t += __shfl_xor(den_t, 16, 64);
    den_t += __shfl_xor(den_t, 32, 64);
    #pragma unroll
    for (int q = 0; q < 10; q++) {
      num_t[q] += __shfl_xor(num_t[q], 16, 64);
      num_t[q] += __shfl_xor(num_t[q], 32, 64);
    }
    if (kg == 0 && col < NC) {
      float* dst = P + (size_t)rb * 1100 + col * 11;
      dst[0] = den_t;
      #pragma unroll
      for (int q = 0; q < 10; q++) dst[1 + q] = num_t[q];
    }
  }
}

// ---- score reduce + select + wcol (merged via last-block ticket, 100 blocks) ----
__global__ __launch_bounds__(256) void k_score_select(const float* __restrict__ P,
    Hdr* h, const float* __restrict__ brk, const float* __restrict__ Wr,
    float* __restrict__ wcol, float* __restrict__ outW, float* __restrict__ outB,
    int* __restrict__ ticket, int k, int nblk) {
  int c = blockIdx.x;           // 0..99
  int tid = threadIdx.x;
  int q = tid % 11, g = tid / 11;   // 23 groups of 11
  float acc = 0.f;
  if (tid < 253) {
    for (int b = g; b < nblk; b += 23)
      acc += P[(size_t)b * 1100 + c * 11 + q];
  }
  __shared__ float red[23][11];
  if (tid < 253) red[g][q] = acc;
  __syncthreads();
  if (tid < 11) {
    float s = 0.f;
    #pragma unroll
    for (int g2 = 0; g2 < 23; g2++) s += red[g2][tid];
    if (tid == 0) h->den[c] = s;
    else h->num[c * 10 + tid - 1] = s;
  }
  __shared__ int sdone;
  __syncthreads();
  __threadfence();
  if (tid == 0) {
    int old = atomicAdd(ticket, 1);
    sdone = (old == NC - 1) ? 1 : 0;
  }
  __syncthreads();
  if (!sdone) return;
  __threadfence();
  __shared__ int sbest;
  if (tid < 12 * SL) { h->r1s[tid] = 0.f; h->r1bs[tid] = 0.f; }
  if (tid == 0) {
    float best = -1.f; int bi = 0;
    for (int cc = 0; cc < NC; cc++) {
      float s = 0.f;
      for (int j = 0; j < 10; j++) { float n = h->num[cc * 10 + j]; s += n * n; }
      float v = s / (h->den[cc] * 10.f);
      if (v > best) { best = v; bi = cc; }
    }
    h->best = bi;
    h->bsel = brk[bi];
    outB[k] = h->bsel;
    sbest = bi;
  }
  __syncthreads();
  int best = sbest;
  for (int d = tid; d < D_IN; d += 256) {
    float v = Wr[(size_t)d * NCP + best];
    wcol[d] = v;
    outW[d * 12 + k] = v;
  }
}

// ---- hc for all rows: one wave per row, float4 loads ----
__global__ __launch_bounds__(256) void k_hc(const float* __restrict__ X,
    const Hdr* __restrict__ h, const float* __restrict__ wcol,
    float* __restrict__ H, float* __restrict__ hc, int k) {
  int lane = threadIdx.x & 63;
  int row = blockIdx.x * 4 + (threadIdx.x >> 6);
  if (row >= N_ROWS) return;
  const float4* xp = (const float4*)(X + (size_t)row * D_IN);
  const float4* wp = (const float4*)wcol;
  float acc = 0.f;
  #pragma unroll
  for (int it = 0; it < 4; it++) {
    int p = lane + it * 64;
    if (p < 196) {
      float4 xv = xp[p], wv = wp[p];
      acc += xv.x * wv.x + xv.y * wv.y + xv.z * wv.z + xv.w * wv.w;
    }
  }
  #pragma unroll
  for (int o = 32; o > 0; o >>= 1) acc += __shfl_xor(acc, o, 64);
  if (lane == 0) {
    float hv = 1.f / (1.f + expf(-(acc + h->bsel)));
    H[(size_t)row * 12 + k] = hv;
    hc[row] = hv;
  }
}

// ---- T^T vec (unnormalized Q columns) with SL-way row-slice split ----
__global__ __launch_bounds__(256) void k_dotQ(const float* __restrict__ Tcm,
    const float* __restrict__ vec, float* __restrict__ dst) {
  int j = blockIdx.x / SL, sl = blockIdx.x % SL;
  const float* q = Tcm + (size_t)j * N_ROWS;
  int i0 = sl * (N_ROWS / SL);
  int i1 = i0 + (N_ROWS / SL);
  float a = 0.f;
  for (int i = i0 + threadIdx.x; i < i1; i += 256) a += q[i] * vec[i];
  __shared__ float red[256];
  red[threadIdx.x] = a;
  __syncthreads();
  for (int s = 128; s > 0; s >>= 1) {
    if (threadIdx.x < s) red[threadIdx.x] += red[threadIdx.x + s];
    __syncthreads();
  }
  if (threadIdx.x == 0) dst[j * SL + sl] = red[0];
}

// ---- t = basev - T cf (cf = raw/(r2_j^2)); writes T[:,k]; partials of t^2, t·Y_j;
//      dofin: last block assembles r2, QT row, R col, backsub (118 blocks) ----
__global__ __launch_bounds__(256) void k_sub_fin(Hdr* h, float* __restrict__ Tcm,
    const float* __restrict__ basev, const float* __restrict__ coefp,
    const float* __restrict__ Y, float* __restrict__ partials,
    float* __restrict__ out_beta, int* __restrict__ ticket, int k, int dofin) {
  __shared__ float cf[12];
  int tid = threadIdx.x;
  if (tid < 12) {
    float s = 0.f;
    #pragma unroll
    for (int s8 = 0; s8 < SL; s8++) s += coefp[tid * SL + s8];
    float r2j = (tid < k) ? h->r2arr[tid] : 1.f;
    cf[tid] = s / (r2j * r2j);
  }
  __syncthreads();
  int i = blockIdx.x * 256 + tid;
  float t = 0.f;
  float v[11];
  #pragma unroll
  for (int q = 0; q < 11; q++) v[q] = 0.f;
  if (i < N_ROWS) {
    t = basev[i];
    for (int j = 0; j < k; j++) t -= Tcm[(size_t)j * N_ROWS + i] * cf[j];
    Tcm[(size_t)k * N_ROWS + i] = t;
    if (dofin) {
      const float* yr = Y + (size_t)i * 10;
      #pragma unroll
      for (int q = 0; q < 10; q++) v[q] = t * yr[q];
      v[10] = t * t;
    }
  }
  if (!dofin) return;
  #pragma unroll
  for (int o = 1; o < 64; o <<= 1) {
    #pragma unroll
    for (int q = 0; q < 11; q++) v[q] += __shfl_xor(v[q], o, 64);
  }
  __shared__ float wred[4][11];
  int wave = tid >> 6, lane = tid & 63;
  if (lane == 0) {
    #pragma unroll
    for (int q = 0; q < 11; q++) wred[wave][q] = v[q];
  }
  __syncthreads();
  if (tid < 11) {
    float s = wred[0][tid] + wred[1][tid] + wred[2][tid] + wred[3][tid];
    partials[blockIdx.x * 12 + tid] = s;
  }
  // ---- last-block finalize ----
  __shared__ int sdone;
  __syncthreads();
  __threadfence();
  if (tid == 0) {
    int old = atomicAdd(ticket, 1);
    sdone = (old == SORT_BLOCKS - 1) ? 1 : 0;
  }
  __syncthreads();
  if (!sdone) return;
  __threadfence();
  __shared__ float red[23][11];
  int q = tid % 11, g = tid / 11;
  float acc2 = 0.f;
  if (tid < 253) {
    for (int b = g; b < SORT_BLOCKS; b += 23)
      acc2 += partials[b * 12 + q];
  }
  if (tid < 253) red[g][q] = acc2;
  __syncthreads();
  __shared__ float s[11];
  __shared__ float Rcol[12];
  __shared__ float r2s;
  if (tid < 11) {
    float ss = 0.f;
    #pragma unroll
    for (int g2 = 0; g2 < 23; g2++) ss += red[g2][tid];
    s[tid] = ss;
  }
  __syncthreads();
  if (tid == 0) {
    float r2 = sqrtf(s[10]);
    h->r2arr[k] = r2;
    h->R[k * 12 + k] = r2;
    r2s = r2;
    Rcol[k] = r2;
    for (int i2 = 0; i2 < k; i2++) {
      float rs = 0.f;
      #pragma unroll
      for (int s8 = 0; s8 < SL; s8++) rs += h->r1s[i2 * SL + s8] + h->r1bs[i2 * SL + s8];
      float Rik = rs / h->r2arr[i2];
      h->R[i2 * 12 + k] = Rik;
      Rcol[i2] = Rik;
    }
  }
  __syncthreads();
  if (tid < 10) {
    float qtk = s[tid] / r2s;
    h->QT[k * 10 + tid] = qtk;
    float bloc[12];
    for (int i2 = k; i2 >= 0; i2--) {
      float t2 = (i2 == k) ? qtk : h->QT[i2 * 10 + tid];
      for (int m = i2 + 1; m <= k; m++) {
        float Rim = (m == k) ? Rcol[i2] : h->R[i2 * 12 + m];
        t2 -= Rim * bloc[m];
      }
      t2 /= ((i2 == k) ? r2s : h->R[i2 * 12 + i2]);
      bloc[i2] = t2;
      h->beta[i2 * 10 + tid] = t2;
      out_beta[i2 * 10 + tid] = t2;
    }
  }
}

static inline int cdiv(int a, int b) { return (a + b - 1) / b; }

extern "C" void kernel_launch(void* const* d_in, const int* in_sizes, int n_in,
                              void* d_out, int out_size, void* d_ws, size_t ws_size,
                              hipStream_t stream) {
  const float* X = (const float*)d_in[0];
  const float* Y = (const float*)d_in[1];
  float* out = (float*)d_out;
  float* outW = out;             // 784*12
  float* outB = out + 9408;      // 12
  float* outBeta = out + 9420;   // 12*10

  char* base = (char*)d_ws;
  Hdr* hdr = (Hdr*)base;
  float* r1p  = (float*)(base + offsetof(Hdr, r1s));
  float* r1bp = (float*)(base + offsetof(Hdr, r1bs));

  size_t off = 16384;
  auto nxt = [&](size_t bytes) -> void* {
    void* p = base + off;
    off += (bytes + 255) & ~(size_t)255;
    return p;
  };
  int* tickets = (int*)nxt(1024);   // [0..11] score, [32..43] subfin
  uint32_t* keysA = (uint32_t*)nxt((size_t)NSEG * SEG * 4);
  uint32_t* keysB = (uint32_t*)nxt((size_t)NSEG * SEG * 4);
  int* valsA = (int*)nxt((size_t)NSEG * SEG * 4);
  int* valsB = (int*)nxt((size_t)NSEG * SEG * 4);
  uint32_t* hs = (uint32_t*)nxt((size_t)NSEG * SORT_BLOCKS * 256 * 4);
  uint32_t* baseA = (uint32_t*)nxt((size_t)NSEG * 256 * 4);
  float* WrAll = (float*)nxt((size_t)NSEG * D_IN * NCP * 4);
  short* WthiAll = (short*)nxt((size_t)NSEG * NCP * KP * 2);
  short* WtloAll = (short*)nxt((size_t)NSEG * NCP * KP * 2);
  float* brAll = (float*)nxt((size_t)NSEG * NC * 4);
  float* wcol = (float*)nxt((size_t)D_IN * 4);
  float* Pbuf = (float*)nxt((size_t)MAXBLK * 1100 * 4);
  float* Tcm = (float*)nxt((size_t)12 * N_ROWS * 4);
  float* Hbuf = (float*)nxt((size_t)N_ROWS * 12 * 4);
  float* hcbuf = (float*)nxt((size_t)N_ROWS * 4);
  float* partials = (float*)nxt(128 * 12 * 4);
  short* Xhi = (short*)nxt((size_t)N_ROWS * KP * 2);
  short* Xlo = (short*)nxt((size_t)N_ROWS * KP * 2);

  hipMemsetAsync(tickets, 0, 1024, stream);

  // 1. RNG key chain + X pre-split
  k_rng_chain<<<1, 64, 0, stream>>>(hdr);
  k_splitX<<<cdiv(N_ROWS * (KP / 8), 256), 256, 0, stream>>>(X, Xhi, Xlo);

  // 2. permutations: 2 rounds x 4 radix passes (keygen fused into pass-0 hist only)
  const int sortgrid = NSEG * SORT_BLOCKS;
  for (int round = 0; round < 2; round++) {
    k_keys_hist<<<sortgrid, 256, 0, stream>>>(hdr, keysA, valsA, hs, round);
    k_scan<<<NSEG, 256, 0, stream>>>(hs, baseA);
    k_scatter<<<sortgrid, 256, 0, stream>>>(keysA, valsA, keysB, valsB, hs, baseA, 0);
    for (int pass = 1; pass < 4; pass++) {
      uint32_t* ik = (pass & 1) ? keysB : keysA;
      uint32_t* ok = (pass & 1) ? keysA : keysB;
      int* iv = (pass & 1) ? valsB : valsA;
      int* ov = (pass & 1) ? valsA : valsB;
      k_hist<<<sortgrid, 256, 0, stream>>>(ik, hs, 8 * pass);
      k_scan<<<NSEG, 256, 0, stream>>>(hs, baseA);
      k_scatter<<<sortgrid, 256, 0, stream>>>(ik, iv, ok, ov, hs, baseA, 8 * pass);
    }
  }

  // 3. candidate weights (fp32 + transposed bf16 hi/lo + biases, one kernel)
  k_gen<<<cdiv(NSEG * NCP * KP, 256), 256, 0, stream>>>(hdr, WrAll, WthiAll, WtloAll, brAll);

  // 4. sequential training loop
  for (int k = 0; k < 12; k++) {
    int bs = 4000 + 2166 * k;
    int nblk_row = cdiv(bs, 64);
    const int* perm = valsA + (size_t)k * SEG;
    const short* Wthi = WthiAll + (size_t)k * NCP * KP;
    const short* Wtlo = WtloAll + (size_t)k * NCP * KP;
    const float* brk = brAll + (size_t)k * NC;

    k_batch_mfma<<<nblk_row * 2, 256, 0, stream>>>(Xhi, Xlo, Wthi, Wtlo, brk, perm, Y, Hbuf, hdr, Pbuf, k, bs);
    k_score_select<<<NC, 256, 0, stream>>>(Pbuf, hdr, brk,
        WrAll + (size_t)k * D_IN * NCP, wcol, outW, outB, &tickets[k], k, nblk_row);
    k_hc<<<7500, 256, 0, stream>>>(X, hdr, wcol, Hbuf, hcbuf, k);
    if (k > 0) k_dotQ<<<k * SL, 256, 0, stream>>>(Tcm, hcbuf, r1p);
    if (k == 1 || k == 2) {
      // reorthogonalize (emulates inv/Householder branches): pass1 no-fin
      k_sub_fin<<<SORT_BLOCKS, 256, 0, stream>>>(hdr, Tcm, hcbuf, r1p, Y, partials,
          outBeta, &tickets[32 + k], k, 0);
      k_dotQ<<<k * SL, 256, 0, stream>>>(Tcm, Tcm + (size_t)k * N_ROWS, r1bp);
      k_sub_fin<<<SORT_BLOCKS, 256, 0, stream>>>(hdr, Tcm, Tcm + (size_t)k * N_ROWS, r1bp,
          Y, partials, outBeta, &tickets[32 + k], k, 1);
    } else {
      k_sub_fin<<<SORT_BLOCKS, 256, 0, stream>>>(hdr, Tcm, hcbuf, r1p, Y, partials,
          outBeta, &tickets[32 + k], k, 1);
    }
  }
}